// Round 1
// 960.745 us; speedup vs baseline: 1.0047x; 1.0047x over previous
//
#include <hip/hip_runtime.h>
#include <cstdint>
#include <cstddef>

// Problem constants
#define NBN   200
#define NS    128
#define ND    1024
#define NDI   2048
#define NST   32
#define NROWS (NBN * NS)          // 25600

typedef __attribute__((ext_vector_type(8))) short bf16x8;   // 8 bf16 = 4 VGPRs
typedef __attribute__((ext_vector_type(4))) float f32x4;

__device__ __forceinline__ unsigned short f2bf(float f) {
    unsigned int u = __float_as_uint(f);
    u += 0x7fffu + ((u >> 16) & 1u);          // round-to-nearest-even
    return (unsigned short)(u >> 16);
}
__device__ __forceinline__ float bf2f(unsigned short h) {
    return __uint_as_float(((unsigned int)h) << 16);
}

// async global->LDS, 16B per lane. LDS dest = wave-uniform base + lane*16.
__device__ __forceinline__ void gl_lds16(const void* g, void* l) {
    typedef __attribute__((address_space(1))) const unsigned int* gp_t;
    typedef __attribute__((address_space(3))) unsigned int* lp_t;
    __builtin_amdgcn_global_load_lds((gp_t)(uintptr_t)g,
                                     (lp_t)(unsigned int)(uintptr_t)l, 16, 0, 0);
}

// ---------------- weight prep: f32 -> bf16 ----------------
__global__ __launch_bounds__(256) void cvt_kernel(const float* __restrict__ src,
                                                  unsigned short* __restrict__ dst, int n) {
    int i = blockIdx.x * 256 + threadIdx.x;
    if (i < n) dst[i] = f2bf(src[i]);
}

// x_proj_W f32 [65,2048] -> padded bf16 [80,2048] (pad rows zero)
__global__ __launch_bounds__(256) void padwx_kernel(const float* __restrict__ src,
                                                    unsigned short* __restrict__ dst) {
    int i = blockIdx.x * 256 + threadIdx.x;   // 80*2048
    int r = i >> 11;
    dst[i] = (r < 65) ? f2bf(src[i]) : (unsigned short)0;
}

// ---------------- LayerNorm: x[row,1024] f32 -> xn bf16 ----------------
__global__ __launch_bounds__(256) void ln_kernel(const float* __restrict__ x,
                                                 const float* __restrict__ gw,
                                                 const float* __restrict__ gb,
                                                 unsigned short* __restrict__ xn) {
    __shared__ float ss[4], ss2[4];
    size_t row = blockIdx.x;
    int tid = threadIdx.x;
    const float4* px = (const float4*)(x + row * ND);
    float4 v = px[tid];
    float s  = v.x + v.y + v.z + v.w;
    float s2 = fmaf(v.x, v.x, fmaf(v.y, v.y, fmaf(v.z, v.z, v.w * v.w)));
    #pragma unroll
    for (int off = 32; off > 0; off >>= 1) {
        s  += __shfl_down(s,  off, 64);
        s2 += __shfl_down(s2, off, 64);
    }
    if ((tid & 63) == 0) { ss[tid >> 6] = s; ss2[tid >> 6] = s2; }
    __syncthreads();
    float tot  = ss[0] + ss[1] + ss[2] + ss[3];
    float tot2 = ss2[0] + ss2[1] + ss2[2] + ss2[3];
    float mu   = tot * (1.f / ND);
    float var  = fmaf(tot2, 1.f / ND, -mu * mu);
    float rstd = rsqrtf(var + 1e-5f);
    float4 wv = ((const float4*)gw)[tid];
    float4 bv = ((const float4*)gb)[tid];
    ushort4 o;
    o.x = f2bf(fmaf((v.x - mu) * rstd, wv.x, bv.x));
    o.y = f2bf(fmaf((v.y - mu) * rstd, wv.y, bv.y));
    o.z = f2bf(fmaf((v.z - mu) * rstd, wv.z, bv.z));
    o.w = f2bf(fmaf((v.w - mu) * rstd, wv.w, bv.w));
    ((ushort4*)(xn + row * ND))[tid] = o;
}

// ================= 256x256 8-phase pipelined MFMA GEMM =================
// C[M,N] = A[M,K] @ B[N,K]^T, bf16 in, f32 acc.
// 512 threads = 8 waves (2M x 4N), per-wave output 128x64, BK=64.
// LDS 128 KiB: A [2buf][kp][256][64B] at 0, B same at +64KiB.
// T2 slot-swizzle: 16B slot ^= (row>>1)&3 (read) ; inverse on global stage src.
// T3/T4: 1 panel (2 x global_load_lds dwordx4) staged per phase; vmcnt(6)
//        once per K-tile (3 panels in flight); prologue 7 panels; peeled tail.
// T5: setprio(1) around each 16-MFMA cluster.  T1: bijective XCD swizzle.

#define BARRIER __builtin_amdgcn_s_barrier()
#define LGKM0  asm volatile("s_waitcnt lgkmcnt(0)" ::: "memory")
#define VMCNT6 asm volatile("s_waitcnt vmcnt(6)" ::: "memory")
#define VMCNT0 asm volatile("s_waitcnt vmcnt(0)" ::: "memory")
#define NOWAIT ((void)0)
#define PRIO1  __builtin_amdgcn_s_setprio(1)
#define PRIO0  __builtin_amdgcn_s_setprio(0)

// stage panel kp of K-tile t (A or B): 2 x gl_lds (rows 0-127, 128-255)
#define STG_A(t, kp) {                                                        \
    gl_lds16(gA0 + (size_t)(t) * 64 + (kp) * 32,                              \
             lA + (((t) & 1) << 15) + ((kp) << 14));                          \
    gl_lds16(gA1 + (size_t)(t) * 64 + (kp) * 32,                              \
             lA + (((t) & 1) << 15) + ((kp) << 14) + 8192); }
#define STG_B(t, kp) {                                                        \
    gl_lds16(gB0 + (size_t)(t) * 64 + (kp) * 32,                              \
             lB + (((t) & 1) << 15) + ((kp) << 14));                          \
    gl_lds16(gB1 + (size_t)(t) * 64 + (kp) * 32,                              \
             lB + (((t) & 1) << 15) + ((kp) << 14) + 8192); }

#define RD_A(dst, mh, kp) { _Pragma("unroll")                                 \
    for (int mi = 0; mi < 4; ++mi)                                            \
        dst[mi] = *(const bf16x8*)(aRd + bo + (kp) * 16384 + (mh) * 4096 + mi * 1024); }
#define RD_B(dst, kp) { _Pragma("unroll")                                     \
    for (int ni = 0; ni < 4; ++ni)                                            \
        dst[ni] = *(const bf16x8*)(bRd + bo + (kp) * 16384 + ni * 1024); }

#define MM(mh, AV, BV) { _Pragma("unroll")                                    \
    for (int mi = 0; mi < 4; ++mi) { _Pragma("unroll")                        \
        for (int ni = 0; ni < 4; ++ni)                                        \
            acc[(mh) * 4 + mi][ni] = __builtin_amdgcn_mfma_f32_16x16x32_bf16( \
                AV[mi], BV[ni], acc[(mh) * 4 + mi][ni], 0, 0, 0); } }

// one K-tile = 4 phases; stages: P0:A-p1(t+1) P1:B-p0(t+2) P2:B-p1(t+2) P3:A-p0(t+2)
#define TILE(t, DO_AP1, DO_T2, W) {                                           \
    const int bo = ((t) & 1) << 15;                                           \
    /* P0: m-lo x kp0 */                                                      \
    RD_A(aK0, 0, 0); RD_B(bK0, 0);                                            \
    if (DO_AP1) STG_A((t) + 1, 1);                                            \
    BARRIER; LGKM0; PRIO1; MM(0, aK0, bK0); PRIO0; BARRIER;                   \
    /* P1: m-lo x kp1 */                                                      \
    RD_A(aK1, 0, 1); RD_B(bK1, 1);                                            \
    if (DO_T2) STG_B((t) + 2, 0);                                             \
    BARRIER; LGKM0; PRIO1; MM(0, aK1, bK1); PRIO0; BARRIER;                   \
    /* P2: m-hi x kp0 */                                                      \
    RD_A(aK0, 1, 0);                                                          \
    if (DO_T2) STG_B((t) + 2, 1);                                             \
    BARRIER; LGKM0; PRIO1; MM(1, aK0, bK0); PRIO0; BARRIER;                   \
    /* P3: m-hi x kp1 */                                                      \
    RD_A(aK1, 1, 1);                                                          \
    if (DO_T2) STG_A((t) + 2, 0);                                             \
    BARRIER; LGKM0; PRIO1; MM(1, aK1, bK1); PRIO0;                            \
    W;                                                                        \
    BARRIER; }

template <int K, int EPI>
__global__ __launch_bounds__(512, 2)
void gemm256(const unsigned short* __restrict__ A,
             const unsigned short* __restrict__ B,
             int N, void* __restrict__ outp, const float* __restrict__ resid) {
    constexpr int NT = K / 64;
    static_assert(NT >= 3, "need >=3 K-tiles");
    __shared__ __align__(16) char smem[131072];

    const int tid  = threadIdx.x;
    const int lane = tid & 63;
    const int wid  = tid >> 6;          // 0..7
    const int lrow = lane & 15;
    const int kq   = lane >> 4;         // 0..3
    const int wmi  = wid >> 2;          // M half  (0..1)
    const int wni  = wid & 3;           // N quarter (0..3)

    // T1: bijective XCD swizzle (nwg % 8 == 0 at both call sites)
    const int gx  = gridDim.x;
    const int nwg = gx * gridDim.y;
    const int lin = blockIdx.y * gx + blockIdx.x;
    const int id2 = (lin & 7) * (nwg >> 3) + (lin >> 3);
    const int bm  = id2 % gx;
    const int bn  = id2 / gx;

    const size_t m0 = (size_t)bm * 256;
    const size_t n0 = (size_t)bn * 256;

    // read bases (T2 swizzled slot; fr is lane-constant for all frag rows)
    const int fr = (lrow >> 1) & 3;
    const char* aRd = smem +          (wmi * 128 + lrow) * 64 + ((kq ^ fr) << 4);
    const char* bRd = smem + 65536 + (wni * 64  + lrow) * 64 + ((kq ^ fr) << 4);

    // stage addressing: lane covers row (wid*16 + lane/4), swizzled 16B slot
    const int srow = wid * 16 + (lane >> 2);
    const int scol = (((lane & 3) ^ ((lane >> 3) & 3)) << 3);   // elements
    const unsigned short* gA0 = A + (m0 + srow) * K + scol;         // rows 0-127
    const unsigned short* gA1 = A + (m0 + 128 + srow) * K + scol;   // rows 128-255
    const unsigned short* gB0 = B + (n0 + srow) * K + scol;
    const unsigned short* gB1 = B + (n0 + 128 + srow) * K + scol;
    char* lA = smem + wid * 1024;
    char* lB = smem + 65536 + wid * 1024;

    f32x4 acc[8][4];
    #pragma unroll
    for (int i = 0; i < 8; ++i)
        #pragma unroll
        for (int j = 0; j < 4; ++j) acc[i][j] = (f32x4){0.f, 0.f, 0.f, 0.f};

    bf16x8 aK0[4], aK1[4], bK0[4], bK1[4];

    // prologue: 7 panels in stream order, then wait with 3 in flight
    STG_B(0, 0); STG_B(0, 1); STG_A(0, 0); STG_A(0, 1);
    STG_B(1, 0); STG_B(1, 1); STG_A(1, 0);
    VMCNT6;
    BARRIER;

    int t = 0;
    #pragma unroll 2
    for (; t < NT - 2; ++t) { TILE(t, 1, 1, VMCNT6); }
    TILE((NT - 2), 1, 0, VMCNT0);
    TILE((NT - 1), 0, 0, NOWAIT);

    // epilogue: C/D layout col=lane&15, row=(lane>>4)*4+r
    #pragma unroll
    for (int mi = 0; mi < 8; ++mi)
        #pragma unroll
        for (int ni = 0; ni < 4; ++ni)
            #pragma unroll
            for (int r = 0; r < 4; ++r) {
                size_t row = m0 + wmi * 128 + mi * 16 + kq * 4 + r;
                size_t col = n0 + wni * 64 + ni * 16 + lrow;
                size_t idx = row * (size_t)N + col;
                float v = acc[mi][ni][r];
                if (EPI == 0) ((unsigned short*)outp)[idx] = f2bf(v);
                else          ((float*)outp)[idx] = v + resid[idx];
            }
}

// ---------------- depthwise causal conv(k=4) + silu ----------------
__global__ __launch_bounds__(256) void conv_silu_kernel(const unsigned short* __restrict__ xz,
                                                        const float* __restrict__ cw,
                                                        const float* __restrict__ cb,
                                                        unsigned short* __restrict__ xact) {
    int tid = blockIdx.x * 256 + threadIdx.x;   // 200*2048
    int c = tid & (NDI - 1);
    int b = tid >> 11;
    float4 wv = ((const float4*)cw)[c];
    float w0 = wv.x, w1 = wv.y, w2 = wv.z, w3 = wv.w;
    float bias = cb[c];
    const unsigned short* px = xz + (size_t)b * NS * (2 * NDI) + c;
    unsigned short* po = xact + (size_t)b * NS * NDI + c;
    float x0 = 0.f, x1 = 0.f, x2 = 0.f;
    for (int t = 0; t < NS; t++) {
        float x3 = bf2f(px[(size_t)t * (2 * NDI)]);
        float v  = fmaf(x3, w3, fmaf(x2, w2, fmaf(x1, w1, fmaf(x0, w0, bias))));
        float s  = v * __builtin_amdgcn_rcpf(1.f + __expf(-v));   // fast silu
        po[(size_t)t * NDI] = f2bf(s);
        x0 = x1; x1 = x2; x2 = x3;
    }
}

// ---------------- GEMM2: x_ssm[25600,80] = x_act[25600,2048] @ Wx[80,2048]^T ----------------
__global__ __launch_bounds__(256, 2)
void gemm2_kernel(const unsigned short* __restrict__ A,
                  const unsigned short* __restrict__ B,
                  float* __restrict__ out) {
    __shared__ __align__(16) unsigned short As[64 * 32];
    __shared__ __align__(16) unsigned short Bs[80 * 32];
    const int tid  = threadIdx.x;
    const int bm   = blockIdx.x;           // 400 blocks of 64 rows
    const int wid  = tid >> 6;
    const int lane = tid & 63;
    const int lrow = lane & 15;
    const int kq   = lane >> 4;

    f32x4 acc[5];
    #pragma unroll
    for (int i = 0; i < 5; i++) acc[i] = (f32x4){0.f, 0.f, 0.f, 0.f};

    const int r1 = tid >> 2;
    const int c8 = (tid & 3) << 3;
    const unsigned short* gA1 = A + ((size_t)bm * 64 + r1) * NDI + c8;
    const unsigned short* gB1 = B + (size_t)r1 * NDI + c8;
    const unsigned short* gB2 = B + (size_t)(64 + r1) * NDI + c8;   // rows 64..79, wave 0 only
    char* lA1 = (char*)As + wid * 1024;
    char* lB1 = (char*)Bs + wid * 1024;
    char* lB2 = (char*)Bs + 4096;

    for (int kt = 0; kt < NDI; kt += 32) {
        __syncthreads();
        gl_lds16(gA1, lA1);
        gl_lds16(gB1, lB1);
        if (tid < 64) gl_lds16(gB2, lB2);
        gA1 += 32; gB1 += 32; gB2 += 32;
        __syncthreads();
        bf16x8 af = *(const bf16x8*)&As[(wid * 16 + lrow) * 32 + kq * 8];
        #pragma unroll
        for (int ni = 0; ni < 5; ni++) {
            bf16x8 bfr = *(const bf16x8*)&Bs[(ni * 16 + lrow) * 32 + kq * 8];
            acc[ni] = __builtin_amdgcn_mfma_f32_16x16x32_bf16(af, bfr, acc[ni], 0, 0, 0);
        }
    }
    #pragma unroll
    for (int ni = 0; ni < 5; ni++)
        #pragma unroll
        for (int r = 0; r < 4; r++) {
            size_t row = (size_t)bm * 64 + wid * 16 + kq * 4 + r;
            int col = ni * 16 + lrow;
            out[row * 80 + col] = acc[ni][r];
        }
}

// ---------------- selective scan + silu(z) gating (slimmed) ----------------
__global__ __launch_bounds__(256)
void scan_kernel(const float* __restrict__ xssm,          // [25600,80]: [dr | B(32) | C(32) | pad]
                 unsigned short* xact_g,                   // in: x_act, out: g (bf16, in-place)
                 const unsigned short* __restrict__ xz,    // z at col 2048, stride 4096
                 const float* __restrict__ dtW,
                 const float* __restrict__ dtb,
                 const float* __restrict__ eb,             // [25600] f32
                 const float* __restrict__ es_p) {
    __shared__ __align__(16) float sB[NS][NST];
    __shared__ __align__(16) float sC[NS][NST];
    __shared__ float sDR[NS];
    __shared__ float sDE[NS];                              // es * emotion_bias
    const int tid = threadIdx.x;
    const int b   = blockIdx.y;
    const int d   = blockIdx.x * 256 + tid;

    for (int i = tid; i < NS * 65; i += 256) {
        int t = i / 65, c = i - t * 65;
        float v = xssm[((size_t)b * NS + t) * 80 + c];
        if (c == 0)      sDR[t] = v;
        else if (c < 33) sB[t][c - 1] = v;
        else             sC[t][c - 33] = v;
    }
    {
        float es = es_p[0];
        for (int i = tid; i < NS; i += 256) sDE[i] = es * eb[b * NS + i];
    }
    __syncthreads();

    const float w  = dtW[d];
    const float bb = dtb[d];
    float h[NST];
    #pragma unroll
    for (int n = 0; n < NST; n++) h[n] = 0.f;

    unsigned short* p        = xact_g + (size_t)b * NS * NDI + d;       // read xa / write g
    const unsigned short* pz = xz + (size_t)b * NS * (2 * NDI) + NDI + d;

    for (int t = 0; t < NS; t++) {
        float xa = bf2f(*p);
        float zz = bf2f(*pz);
        float raw = fmaf(sDR[t], w, bb);
        float sp  = (raw > 20.f) ? raw : __logf(1.f + __expf(raw));     // hw exp/log softplus
        float delta = fmaxf(sp + sDE[t], 1e-4f);
        float a = __expf(-delta);
        float y = 0.f;
        #pragma unroll
        for (int n8 = 0; n8 < 8; n8++) {
            f32x4 Bv = *(const f32x4*)&sB[t][n8 * 4];
            f32x4 Cv = *(const f32x4*)&sC[t][n8 * 4];
            #pragma unroll
            for (int j = 0; j < 4; j++) {
                h[n8 * 4 + j] = fmaf(h[n8 * 4 + j], a, Bv[j] * xa);
                y = fmaf(h[n8 * 4 + j], Cv[j], y);
            }
        }
        float sig = __builtin_amdgcn_rcpf(1.f + __expf(-zz));           // fast sigmoid
        *p = f2bf(y * zz * sig);
        p += NDI; pz += 2 * NDI;
    }
}

// ---------------- launch ----------------
extern "C" void kernel_launch(void* const* d_in, const int* in_sizes, int n_in,
                              void* d_out, int out_size, void* d_ws, size_t ws_size,
                              hipStream_t stream) {
    const float* x   = (const float*)d_in[0];
    const float* eb  = (const float*)d_in[1];
    const float* nw  = (const float*)d_in[2];
    const float* nb  = (const float*)d_in[3];
    const float* Wi  = (const float*)d_in[4];
    const float* cw  = (const float*)d_in[5];
    const float* cb  = (const float*)d_in[6];
    const float* Wx  = (const float*)d_in[7];
    const float* dtW = (const float*)d_in[8];
    const float* dtb = (const float*)d_in[9];
    const float* Wo  = (const float*)d_in[10];
    const float* es  = (const float*)d_in[11];
    float* out = (float*)d_out;                     // FLOAT32 output

    // workspace layout (bytes, 256-aligned); xn aliases xact (dead after GEMM1)
    char* ws = (char*)d_ws;
    unsigned short* wi_b   = (unsigned short*)(ws + 0);            //  8,388,608
    unsigned short* wo_b   = (unsigned short*)(ws + 8388608);      //  4,194,304
    unsigned short* wx_b   = (unsigned short*)(ws + 12582912);     //    327,680
    unsigned short* xz_b   = (unsigned short*)(ws + 12910592);     // 209,715,200
    unsigned short* xact_b = (unsigned short*)(ws + 222625792);    // 104,857,600 (hosts xn first)
    float*          xssm   = (float*)(ws + 327483392);             //  8,192,000 -> total 335,675,392
    if (ws_size < (size_t)335675392) return;

    // 1. weights -> bf16
    cvt_kernel<<<(2 * NDI * ND + 255) / 256, 256, 0, stream>>>(Wi, wi_b, 2 * NDI * ND);
    cvt_kernel<<<(ND * NDI + 255) / 256, 256, 0, stream>>>(Wo, wo_b, ND * NDI);
    padwx_kernel<<<(80 * NDI) / 256, 256, 0, stream>>>(Wx, wx_b);

    // 2. LayerNorm -> xn (bf16), staged in xact region
    unsigned short* xn_b = xact_b;
    ln_kernel<<<NROWS, 256, 0, stream>>>(x, nw, nb, xn_b);

    // 3. GEMM1: xz = xn @ Wi^T   [25600,4096] bf16   (256^2 8-phase)
    gemm256<ND, 0><<<dim3(NROWS / 256, (2 * NDI) / 256), 512, 0, stream>>>(
        xn_b, wi_b, 2 * NDI, xz_b, nullptr);

    // 4. conv + silu -> x_act (overwrites xn region; xn dead)
    conv_silu_kernel<<<(NBN * NDI) / 256, 256, 0, stream>>>(xz_b, cw, cb, xact_b);

    // 5. GEMM2: x_ssm = x_act @ Wx^T  [25600,80] f32
    gemm2_kernel<<<NROWS / 64, 256, 0, stream>>>(xact_b, wx_b, xssm);

    // 6. scan + gating (g overwrites x_act)
    scan_kernel<<<dim3(NDI / 256, NBN), 256, 0, stream>>>(xssm, xact_b, xz_b, dtW, dtb, eb, es);

    // 7. GEMM3: out = g @ Wo^T + residual  (FLOAT32 store, 256^2 8-phase)
    gemm256<NDI, 1><<<dim3(NROWS / 256, ND / 256), 512, 0, stream>>>(
        xact_b, wo_b, ND, out, x);
}

// Round 2
// 882.402 us; speedup vs baseline: 1.0939x; 1.0888x over previous
//
#include <hip/hip_runtime.h>
#include <cstdint>
#include <cstddef>

// Problem constants
#define NBN   200
#define NS    128
#define ND    1024
#define NDI   2048
#define NST   32
#define NROWS (NBN * NS)          // 25600

typedef __attribute__((ext_vector_type(8))) short bf16x8;   // 8 bf16 = 4 VGPRs
typedef __attribute__((ext_vector_type(4))) float f32x4;

__device__ __forceinline__ unsigned short f2bf(float f) {
    unsigned int u = __float_as_uint(f);
    u += 0x7fffu + ((u >> 16) & 1u);          // round-to-nearest-even
    return (unsigned short)(u >> 16);
}
__device__ __forceinline__ float bf2f(unsigned short h) {
    return __uint_as_float(((unsigned int)h) << 16);
}

// async global->LDS, 16B per lane. LDS dest = wave-uniform base + lane*16.
__device__ __forceinline__ void gl_lds16(const void* g, void* l) {
    typedef __attribute__((address_space(1))) const unsigned int* gp_t;
    typedef __attribute__((address_space(3))) unsigned int* lp_t;
    __builtin_amdgcn_global_load_lds((gp_t)(uintptr_t)g,
                                     (lp_t)(unsigned int)(uintptr_t)l, 16, 0, 0);
}

// ---------------- weight prep: f32 -> bf16 ----------------
__global__ __launch_bounds__(256) void cvt_kernel(const float* __restrict__ src,
                                                  unsigned short* __restrict__ dst, int n) {
    int i = blockIdx.x * 256 + threadIdx.x;
    if (i < n) dst[i] = f2bf(src[i]);
}

// x_proj_W f32 [65,2048] -> padded bf16 [80,2048] (pad rows zero)
__global__ __launch_bounds__(256) void padwx_kernel(const float* __restrict__ src,
                                                    unsigned short* __restrict__ dst) {
    int i = blockIdx.x * 256 + threadIdx.x;   // 80*2048
    int r = i >> 11;
    dst[i] = (r < 65) ? f2bf(src[i]) : (unsigned short)0;
}

// ---------------- LayerNorm: x[row,1024] f32 -> xn bf16 ----------------
__global__ __launch_bounds__(256) void ln_kernel(const float* __restrict__ x,
                                                 const float* __restrict__ gw,
                                                 const float* __restrict__ gb,
                                                 unsigned short* __restrict__ xn) {
    __shared__ float ss[4], ss2[4];
    size_t row = blockIdx.x;
    int tid = threadIdx.x;
    const float4* px = (const float4*)(x + row * ND);
    float4 v = px[tid];
    float s  = v.x + v.y + v.z + v.w;
    float s2 = fmaf(v.x, v.x, fmaf(v.y, v.y, fmaf(v.z, v.z, v.w * v.w)));
    #pragma unroll
    for (int off = 32; off > 0; off >>= 1) {
        s  += __shfl_down(s,  off, 64);
        s2 += __shfl_down(s2, off, 64);
    }
    if ((tid & 63) == 0) { ss[tid >> 6] = s; ss2[tid >> 6] = s2; }
    __syncthreads();
    float tot  = ss[0] + ss[1] + ss[2] + ss[3];
    float tot2 = ss2[0] + ss2[1] + ss2[2] + ss2[3];
    float mu   = tot * (1.f / ND);
    float var  = fmaf(tot2, 1.f / ND, -mu * mu);
    float rstd = rsqrtf(var + 1e-5f);
    float4 wv = ((const float4*)gw)[tid];
    float4 bv = ((const float4*)gb)[tid];
    ushort4 o;
    o.x = f2bf(fmaf((v.x - mu) * rstd, wv.x, bv.x));
    o.y = f2bf(fmaf((v.y - mu) * rstd, wv.y, bv.y));
    o.z = f2bf(fmaf((v.z - mu) * rstd, wv.z, bv.z));
    o.w = f2bf(fmaf((v.w - mu) * rstd, wv.w, bv.w));
    ((ushort4*)(xn + row * ND))[tid] = o;
}

// ================= 256x256 8-phase pipelined MFMA GEMM =================
// C[M,N] = A[M,K] @ B[N,K]^T, bf16 in, f32 acc.  (unchanged this round)

#define BARRIER __builtin_amdgcn_s_barrier()
#define LGKM0  asm volatile("s_waitcnt lgkmcnt(0)" ::: "memory")
#define VMCNT6 asm volatile("s_waitcnt vmcnt(6)" ::: "memory")
#define VMCNT0 asm volatile("s_waitcnt vmcnt(0)" ::: "memory")
#define NOWAIT ((void)0)
#define PRIO1  __builtin_amdgcn_s_setprio(1)
#define PRIO0  __builtin_amdgcn_s_setprio(0)

#define STG_A(t, kp) {                                                        \
    gl_lds16(gA0 + (size_t)(t) * 64 + (kp) * 32,                              \
             lA + (((t) & 1) << 15) + ((kp) << 14));                          \
    gl_lds16(gA1 + (size_t)(t) * 64 + (kp) * 32,                              \
             lA + (((t) & 1) << 15) + ((kp) << 14) + 8192); }
#define STG_B(t, kp) {                                                        \
    gl_lds16(gB0 + (size_t)(t) * 64 + (kp) * 32,                              \
             lB + (((t) & 1) << 15) + ((kp) << 14));                          \
    gl_lds16(gB1 + (size_t)(t) * 64 + (kp) * 32,                              \
             lB + (((t) & 1) << 15) + ((kp) << 14) + 8192); }

#define RD_A(dst, mh, kp) { _Pragma("unroll")                                 \
    for (int mi = 0; mi < 4; ++mi)                                            \
        dst[mi] = *(const bf16x8*)(aRd + bo + (kp) * 16384 + (mh) * 4096 + mi * 1024); }
#define RD_B(dst, kp) { _Pragma("unroll")                                     \
    for (int ni = 0; ni < 4; ++ni)                                            \
        dst[ni] = *(const bf16x8*)(bRd + bo + (kp) * 16384 + ni * 1024); }

#define MM(mh, AV, BV) { _Pragma("unroll")                                    \
    for (int mi = 0; mi < 4; ++mi) { _Pragma("unroll")                        \
        for (int ni = 0; ni < 4; ++ni)                                        \
            acc[(mh) * 4 + mi][ni] = __builtin_amdgcn_mfma_f32_16x16x32_bf16( \
                AV[mi], BV[ni], acc[(mh) * 4 + mi][ni], 0, 0, 0); } }

#define TILE(t, DO_AP1, DO_T2, W) {                                           \
    const int bo = ((t) & 1) << 15;                                           \
    RD_A(aK0, 0, 0); RD_B(bK0, 0);                                            \
    if (DO_AP1) STG_A((t) + 1, 1);                                            \
    BARRIER; LGKM0; PRIO1; MM(0, aK0, bK0); PRIO0; BARRIER;                   \
    RD_A(aK1, 0, 1); RD_B(bK1, 1);                                            \
    if (DO_T2) STG_B((t) + 2, 0);                                             \
    BARRIER; LGKM0; PRIO1; MM(0, aK1, bK1); PRIO0; BARRIER;                   \
    RD_A(aK0, 1, 0);                                                          \
    if (DO_T2) STG_B((t) + 2, 1);                                             \
    BARRIER; LGKM0; PRIO1; MM(1, aK0, bK0); PRIO0; BARRIER;                   \
    RD_A(aK1, 1, 1);                                                          \
    if (DO_T2) STG_A((t) + 2, 0);                                             \
    BARRIER; LGKM0; PRIO1; MM(1, aK1, bK1); PRIO0;                            \
    W;                                                                        \
    BARRIER; }

template <int K, int EPI>
__global__ __launch_bounds__(512, 2)
void gemm256(const unsigned short* __restrict__ A,
             const unsigned short* __restrict__ B,
             int N, void* __restrict__ outp, const float* __restrict__ resid) {
    constexpr int NT = K / 64;
    static_assert(NT >= 3, "need >=3 K-tiles");
    __shared__ __align__(16) char smem[131072];

    const int tid  = threadIdx.x;
    const int lane = tid & 63;
    const int wid  = tid >> 6;
    const int lrow = lane & 15;
    const int kq   = lane >> 4;
    const int wmi  = wid >> 2;
    const int wni  = wid & 3;

    const int gx  = gridDim.x;
    const int nwg = gx * gridDim.y;
    const int lin = blockIdx.y * gx + blockIdx.x;
    const int id2 = (lin & 7) * (nwg >> 3) + (lin >> 3);
    const int bm  = id2 % gx;
    const int bn  = id2 / gx;

    const size_t m0 = (size_t)bm * 256;
    const size_t n0 = (size_t)bn * 256;

    const int fr = (lrow >> 1) & 3;
    const char* aRd = smem +          (wmi * 128 + lrow) * 64 + ((kq ^ fr) << 4);
    const char* bRd = smem + 65536 + (wni * 64  + lrow) * 64 + ((kq ^ fr) << 4);

    const int srow = wid * 16 + (lane >> 2);
    const int scol = (((lane & 3) ^ ((lane >> 3) & 3)) << 3);
    const unsigned short* gA0 = A + (m0 + srow) * K + scol;
    const unsigned short* gA1 = A + (m0 + 128 + srow) * K + scol;
    const unsigned short* gB0 = B + (n0 + srow) * K + scol;
    const unsigned short* gB1 = B + (n0 + 128 + srow) * K + scol;
    char* lA = smem + wid * 1024;
    char* lB = smem + 65536 + wid * 1024;

    f32x4 acc[8][4];
    #pragma unroll
    for (int i = 0; i < 8; ++i)
        #pragma unroll
        for (int j = 0; j < 4; ++j) acc[i][j] = (f32x4){0.f, 0.f, 0.f, 0.f};

    bf16x8 aK0[4], aK1[4], bK0[4], bK1[4];

    STG_B(0, 0); STG_B(0, 1); STG_A(0, 0); STG_A(0, 1);
    STG_B(1, 0); STG_B(1, 1); STG_A(1, 0);
    VMCNT6;
    BARRIER;

    int t = 0;
    #pragma unroll 2
    for (; t < NT - 2; ++t) { TILE(t, 1, 1, VMCNT6); }
    TILE((NT - 2), 1, 0, VMCNT0);
    TILE((NT - 1), 0, 0, NOWAIT);

    #pragma unroll
    for (int mi = 0; mi < 8; ++mi)
        #pragma unroll
        for (int ni = 0; ni < 4; ++ni)
            #pragma unroll
            for (int r = 0; r < 4; ++r) {
                size_t row = m0 + wmi * 128 + mi * 16 + kq * 4 + r;
                size_t col = n0 + wni * 64 + ni * 16 + lrow;
                size_t idx = row * (size_t)N + col;
                float v = acc[mi][ni][r];
                if (EPI == 0) ((unsigned short*)outp)[idx] = f2bf(v);
                else          ((float*)outp)[idx] = v + resid[idx];
            }
}

// ---------------- depthwise causal conv(k=4) + silu ----------------
__global__ __launch_bounds__(256) void conv_silu_kernel(const unsigned short* __restrict__ xz,
                                                        const float* __restrict__ cw,
                                                        const float* __restrict__ cb,
                                                        unsigned short* __restrict__ xact) {
    int tid = blockIdx.x * 256 + threadIdx.x;   // 200*2048
    int c = tid & (NDI - 1);
    int b = tid >> 11;
    float4 wv = ((const float4*)cw)[c];
    float w0 = wv.x, w1 = wv.y, w2 = wv.z, w3 = wv.w;
    float bias = cb[c];
    const unsigned short* px = xz + (size_t)b * NS * (2 * NDI) + c;
    unsigned short* po = xact + (size_t)b * NS * NDI + c;
    float x0 = 0.f, x1 = 0.f, x2 = 0.f;
    for (int t = 0; t < NS; t++) {
        float x3 = bf2f(px[(size_t)t * (2 * NDI)]);
        float v  = fmaf(x3, w3, fmaf(x2, w2, fmaf(x1, w1, fmaf(x0, w0, bias))));
        float s  = v * __builtin_amdgcn_rcpf(1.f + __expf(-v));   // fast silu
        po[(size_t)t * NDI] = f2bf(s);
        x0 = x1; x1 = x2; x2 = x3;
    }
}

// ---------------- GEMM2: x_ssm[25600,80] = x_act[25600,2048] @ Wx[80,2048]^T ----------------
__global__ __launch_bounds__(256, 2)
void gemm2_kernel(const unsigned short* __restrict__ A,
                  const unsigned short* __restrict__ B,
                  float* __restrict__ out) {
    __shared__ __align__(16) unsigned short As[64 * 32];
    __shared__ __align__(16) unsigned short Bs[80 * 32];
    const int tid  = threadIdx.x;
    const int bm   = blockIdx.x;
    const int wid  = tid >> 6;
    const int lane = tid & 63;
    const int lrow = lane & 15;
    const int kq   = lane >> 4;

    f32x4 acc[5];
    #pragma unroll
    for (int i = 0; i < 5; i++) acc[i] = (f32x4){0.f, 0.f, 0.f, 0.f};

    const int r1 = tid >> 2;
    const int c8 = (tid & 3) << 3;
    const unsigned short* gA1 = A + ((size_t)bm * 64 + r1) * NDI + c8;
    const unsigned short* gB1 = B + (size_t)r1 * NDI + c8;
    const unsigned short* gB2 = B + (size_t)(64 + r1) * NDI + c8;
    char* lA1 = (char*)As + wid * 1024;
    char* lB1 = (char*)Bs + wid * 1024;
    char* lB2 = (char*)Bs + 4096;

    for (int kt = 0; kt < NDI; kt += 32) {
        __syncthreads();
        gl_lds16(gA1, lA1);
        gl_lds16(gB1, lB1);
        if (tid < 64) gl_lds16(gB2, lB2);
        gA1 += 32; gB1 += 32; gB2 += 32;
        __syncthreads();
        bf16x8 af = *(const bf16x8*)&As[(wid * 16 + lrow) * 32 + kq * 8];
        #pragma unroll
        for (int ni = 0; ni < 5; ni++) {
            bf16x8 bfr = *(const bf16x8*)&Bs[(ni * 16 + lrow) * 32 + kq * 8];
            acc[ni] = __builtin_amdgcn_mfma_f32_16x16x32_bf16(af, bfr, acc[ni], 0, 0, 0);
        }
    }
    #pragma unroll
    for (int ni = 0; ni < 5; ni++)
        #pragma unroll
        for (int r = 0; r < 4; r++) {
            size_t row = (size_t)bm * 64 + wid * 16 + kq * 4 + r;
            int col = ni * 16 + lrow;
            out[row * 80 + col] = acc[ni][r];
        }
}

// ================= SSD chunked selective scan (replaces scan_kernel) =================
// Per block: (b, 256-d slice). 4 chunks of T=32 steps, h0 carried in LDS.
// y[t,d] = Einv[t,d]*( C@h0 + Gmask@P )[t,d],  P[s,d]=xa*exp(L'[s,d]),
// h0' = Einv[31,d]*(h0 + B^T@P).  G[t,s]=sum_n C[t,n]B[s,n] shared over d.
// Output g = y*silu(z) written in-place over x_act (bf16).
__global__ __launch_bounds__(256, 2)
void ssd_kernel(const float* __restrict__ xssm,          // [25600,80]: [dr | B(32) | C(32) | pad]
                unsigned short* xact_g,                   // in: x_act, out: g (bf16, in-place)
                const unsigned short* __restrict__ xz,    // z at col 2048, stride 4096
                const float* __restrict__ dtW,
                const float* __restrict__ dtb,
                const float* __restrict__ eb,             // [25600] f32
                const float* __restrict__ es_p) {
    __shared__ float sDR[32], sDE[32];
    __shared__ __align__(16) unsigned short sC[32][32];    // [t][n]
    __shared__ __align__(16) unsigned short sB[32][32];    // [s][n]
    __shared__ __align__(16) unsigned short sBt[32][32];   // [n][s]
    __shared__ __align__(16) unsigned short sG[32][32];    // [t][s] swz
    __shared__ __align__(16) unsigned short sP[256][32];   // [dloc][s] swz (wave-local)
    __shared__ __align__(16) float          sE[256][32];   // [dloc][t] swz, Einv=exp(-L')
    __shared__ __align__(16) unsigned short sH[256][32];   // [dloc][n] h0 bf16

    const int tid  = threadIdx.x;
    const int b    = blockIdx.y;
    const int d0   = blockIdx.x * 256;
    const int lane = tid & 63;
    const int wid  = tid >> 6;
    const int lrow = lane & 15;
    const int kq   = lane >> 4;
    const int wd0  = wid * 64;

    const float w  = dtW[d0 + tid];
    const float bb = dtb[d0 + tid];
    const float es = es_p[0];

    // h0 = 0
    for (int i = tid; i < 256 * 32; i += 256) ((unsigned short*)sH)[i] = 0;

    #pragma unroll 1
    for (int c = 0; c < 4; ++c) {
        __syncthreads();                         // protect staging vs prev readers
        // ---- stage xssm chunk slice + emotion bias ----
        {
            const float* src = xssm + ((size_t)b * 128 + c * 32) * 80;
            for (int i = tid; i < 2560; i += 256) {
                int t = i / 80, col = i - t * 80;
                float v = src[i];
                if (col == 0) sDR[t] = v;
                else if (col < 33) {
                    unsigned short bv = f2bf(v);
                    sB[t][col - 1] = bv;
                    sBt[col - 1][t] = bv;
                } else if (col < 65) sC[t][col - 33] = f2bf(v);
            }
            if (tid < 32) sDE[tid] = es * eb[b * 128 + c * 32 + tid];
        }
        __syncthreads();

        // ---- G = C B^T with causal mask (wave wid -> fragment wid) ----
        {
            int mi = wid >> 1, ni = wid & 1;
            bf16x8 af = *(const bf16x8*)&sC[mi * 16 + lrow][kq * 8];
            bf16x8 bf = *(const bf16x8*)&sB[ni * 16 + lrow][kq * 8];
            f32x4 z4 = (f32x4){0.f, 0.f, 0.f, 0.f};
            f32x4 g = __builtin_amdgcn_mfma_f32_16x16x32_bf16(af, bf, z4, 0, 0, 0);
            #pragma unroll
            for (int r = 0; r < 4; ++r) {
                int t = mi * 16 + kq * 4 + r, s = ni * 16 + lrow;
                float val = (s <= t) ? g[r] : 0.f;
                *(unsigned short*)((char*)sG + t * 64 +
                    ((((s >> 3) ^ (t & 3)) << 4) | ((s & 7) << 1))) = f2bf(val);
            }
        }

        // ---- P/E gen: serial 32-step prefix per thread (dloc = tid) ----
        {
            const unsigned short* pxa =
                xact_g + ((size_t)b * 128 + c * 32) * 2048 + d0 + tid;
            float L = 0.f;
            for (int t8 = 0; t8 < 4; ++t8) {
                bf16x8 pv;
                #pragma unroll
                for (int j = 0; j < 8; ++j) {
                    int t = t8 * 8 + j;
                    float raw = fmaf(sDR[t], w, bb);
                    float sp  = (raw > 20.f) ? raw : __logf(1.f + __expf(raw));
                    float delta = fmaxf(sp + sDE[t], 1e-4f);
                    L += delta;
                    float xa = bf2f(pxa[(size_t)t * 2048]);
                    pv[j] = (short)f2bf(xa * __expf(L));
                    *(float*)((char*)sE + tid * 128 +
                        ((((t >> 2) ^ (tid & 7)) << 4) | ((t & 3) << 2))) = __expf(-L);
                }
                *(bf16x8*)((char*)sP + tid * 64 + (((t8 ^ (tid & 3)) << 4))) = pv;
            }
        }
        __syncthreads();

        // ---- MFMA phase: acc = C@h0 + Gmask@P ; racc = B^T@P ----
        f32x4 acc[2][4], racc[2][4];
        bf16x8 cfrag[2], gfrag[2], btfrag[2], hfrag[4], pfrag[4];
        #pragma unroll
        for (int mi = 0; mi < 2; ++mi) {
            int tr = mi * 16 + lrow;
            cfrag[mi]  = *(const bf16x8*)&sC[tr][kq * 8];
            gfrag[mi]  = *(const bf16x8*)((const char*)sG + tr * 64 +
                                          (((kq ^ (tr & 3)) << 4)));
            btfrag[mi] = *(const bf16x8*)&sBt[tr][kq * 8];
        }
        #pragma unroll
        for (int ni = 0; ni < 4; ++ni) {
            int dc = wd0 + ni * 16 + lrow;
            hfrag[ni] = *(const bf16x8*)&sH[dc][kq * 8];
            pfrag[ni] = *(const bf16x8*)((const char*)sP + dc * 64 +
                                         (((kq ^ (dc & 3)) << 4)));
        }
        #pragma unroll
        for (int mi = 0; mi < 2; ++mi)
            #pragma unroll
            for (int ni = 0; ni < 4; ++ni) {
                f32x4 z4 = (f32x4){0.f, 0.f, 0.f, 0.f};
                acc[mi][ni] = __builtin_amdgcn_mfma_f32_16x16x32_bf16(
                    cfrag[mi], hfrag[ni], z4, 0, 0, 0);
                acc[mi][ni] = __builtin_amdgcn_mfma_f32_16x16x32_bf16(
                    gfrag[mi], pfrag[ni], acc[mi][ni], 0, 0, 0);
                racc[mi][ni] = __builtin_amdgcn_mfma_f32_16x16x32_bf16(
                    btfrag[mi], pfrag[ni], z4, 0, 0, 0);
            }

        // ---- epilogue: g = Einv*acc * silu(z), in-place over x_act ----
        #pragma unroll
        for (int mi = 0; mi < 2; ++mi)
            #pragma unroll
            for (int ni = 0; ni < 4; ++ni) {
                int dc = wd0 + ni * 16 + lrow;
                f32x4 ev = *(const f32x4*)((const char*)sE + dc * 128 +
                                           ((((mi * 4 + kq) ^ (dc & 7)) << 4)));
                size_t rowg = (size_t)b * 128 + c * 32 + mi * 16 + kq * 4;
                #pragma unroll
                for (int r = 0; r < 4; ++r) {
                    float y  = acc[mi][ni][r] * ev[r];
                    float zz = bf2f(xz[(rowg + r) * 4096 + 2048 + d0 + dc]);
                    float sig = __builtin_amdgcn_rcpf(1.f + __expf(-zz));
                    xact_g[(rowg + r) * 2048 + d0 + dc] = f2bf(y * zz * sig);
                }
            }

        // ---- h0 update (wave-local d range): h0' = Einv[31]*(h0 + R) ----
        #pragma unroll
        for (int ni = 0; ni < 4; ++ni) {
            int dc = wd0 + ni * 16 + lrow;
            float e31 = *(const float*)((const char*)sE + dc * 128 +
                                        (((7 ^ (dc & 7)) << 4) | 12));
            #pragma unroll
            for (int mi = 0; mi < 2; ++mi)
                #pragma unroll
                for (int r = 0; r < 4; ++r) {
                    int n = mi * 16 + kq * 4 + r;
                    float h = bf2f(sH[dc][n]) + racc[mi][ni][r];
                    sH[dc][n] = f2bf(e31 * h);
                }
        }
    }
}

// ---------------- launch ----------------
extern "C" void kernel_launch(void* const* d_in, const int* in_sizes, int n_in,
                              void* d_out, int out_size, void* d_ws, size_t ws_size,
                              hipStream_t stream) {
    const float* x   = (const float*)d_in[0];
    const float* eb  = (const float*)d_in[1];
    const float* nw  = (const float*)d_in[2];
    const float* nb  = (const float*)d_in[3];
    const float* Wi  = (const float*)d_in[4];
    const float* cw  = (const float*)d_in[5];
    const float* cb  = (const float*)d_in[6];
    const float* Wx  = (const float*)d_in[7];
    const float* dtW = (const float*)d_in[8];
    const float* dtb = (const float*)d_in[9];
    const float* Wo  = (const float*)d_in[10];
    const float* es  = (const float*)d_in[11];
    float* out = (float*)d_out;                     // FLOAT32 output

    // workspace layout (bytes, 256-aligned); xn aliases xact (dead after GEMM1)
    char* ws = (char*)d_ws;
    unsigned short* wi_b   = (unsigned short*)(ws + 0);            //  8,388,608
    unsigned short* wo_b   = (unsigned short*)(ws + 8388608);      //  4,194,304
    unsigned short* wx_b   = (unsigned short*)(ws + 12582912);     //    327,680
    unsigned short* xz_b   = (unsigned short*)(ws + 12910592);     // 209,715,200
    unsigned short* xact_b = (unsigned short*)(ws + 222625792);    // 104,857,600 (hosts xn first)
    float*          xssm   = (float*)(ws + 327483392);             //  8,192,000 -> total 335,675,392
    if (ws_size < (size_t)335675392) return;

    // 1. weights -> bf16
    cvt_kernel<<<(2 * NDI * ND + 255) / 256, 256, 0, stream>>>(Wi, wi_b, 2 * NDI * ND);
    cvt_kernel<<<(ND * NDI + 255) / 256, 256, 0, stream>>>(Wo, wo_b, ND * NDI);
    padwx_kernel<<<(80 * NDI) / 256, 256, 0, stream>>>(Wx, wx_b);

    // 2. LayerNorm -> xn (bf16), staged in xact region
    unsigned short* xn_b = xact_b;
    ln_kernel<<<NROWS, 256, 0, stream>>>(x, nw, nb, xn_b);

    // 3. GEMM1: xz = xn @ Wi^T   [25600,4096] bf16   (256^2 8-phase)
    gemm256<ND, 0><<<dim3(NROWS / 256, (2 * NDI) / 256), 512, 0, stream>>>(
        xn_b, wi_b, 2 * NDI, xz_b, nullptr);

    // 4. conv + silu -> x_act (overwrites xn region; xn dead)
    conv_silu_kernel<<<(NBN * NDI) / 256, 256, 0, stream>>>(xz_b, cw, cb, xact_b);

    // 5. GEMM2: x_ssm = x_act @ Wx^T  [25600,80] f32
    gemm2_kernel<<<NROWS / 64, 256, 0, stream>>>(xact_b, wx_b, xssm);

    // 6. SSD chunked scan + gating (g overwrites x_act)
    ssd_kernel<<<dim3(NDI / 256, NBN), 256, 0, stream>>>(xssm, xact_b, xz_b, dtW, dtb, eb, es);

    // 7. GEMM3: out = g @ Wo^T + residual  (FLOAT32 store, 256^2 8-phase)
    gemm256<NDI, 1><<<dim3(NROWS / 256, ND / 256), 512, 0, stream>>>(
        xact_b, wo_b, ND, out, x);
}

// Round 3
// 866.914 us; speedup vs baseline: 1.1134x; 1.0179x over previous
//
#include <hip/hip_runtime.h>
#include <cstdint>
#include <cstddef>

// Problem constants
#define NBN   200
#define NS    128
#define ND    1024
#define NDI   2048
#define NST   32
#define NROWS (NBN * NS)          // 25600

typedef __attribute__((ext_vector_type(8))) short bf16x8;   // 8 bf16 = 4 VGPRs
typedef __attribute__((ext_vector_type(4))) float f32x4;

__device__ __forceinline__ unsigned short f2bf(float f) {
    unsigned int u = __float_as_uint(f);
    u += 0x7fffu + ((u >> 16) & 1u);          // round-to-nearest-even
    return (unsigned short)(u >> 16);
}
__device__ __forceinline__ float bf2f(unsigned short h) {
    return __uint_as_float(((unsigned int)h) << 16);
}

// async global->LDS, 16B per lane. LDS dest = wave-uniform base + lane*16.
__device__ __forceinline__ void gl_lds16(const void* g, void* l) {
    typedef __attribute__((address_space(1))) const unsigned int* gp_t;
    typedef __attribute__((address_space(3))) unsigned int* lp_t;
    __builtin_amdgcn_global_load_lds((gp_t)(uintptr_t)g,
                                     (lp_t)(unsigned int)(uintptr_t)l, 16, 0, 0);
}

// ---------------- weight prep: f32 -> bf16 ----------------
__global__ __launch_bounds__(256) void cvt_kernel(const float* __restrict__ src,
                                                  unsigned short* __restrict__ dst, int n) {
    int i = blockIdx.x * 256 + threadIdx.x;
    if (i < n) dst[i] = f2bf(src[i]);
}

// x_proj_W f32 [65,2048] -> padded bf16 [80,2048] (pad rows zero)
__global__ __launch_bounds__(256) void padwx_kernel(const float* __restrict__ src,
                                                    unsigned short* __restrict__ dst) {
    int i = blockIdx.x * 256 + threadIdx.x;   // 80*2048
    int r = i >> 11;
    dst[i] = (r < 65) ? f2bf(src[i]) : (unsigned short)0;
}

// ---------------- LayerNorm: x[row,1024] f32 -> xn bf16 ----------------
__global__ __launch_bounds__(256) void ln_kernel(const float* __restrict__ x,
                                                 const float* __restrict__ gw,
                                                 const float* __restrict__ gb,
                                                 unsigned short* __restrict__ xn) {
    __shared__ float ss[4], ss2[4];
    size_t row = blockIdx.x;
    int tid = threadIdx.x;
    const float4* px = (const float4*)(x + row * ND);
    float4 v = px[tid];
    float s  = v.x + v.y + v.z + v.w;
    float s2 = fmaf(v.x, v.x, fmaf(v.y, v.y, fmaf(v.z, v.z, v.w * v.w)));
    #pragma unroll
    for (int off = 32; off > 0; off >>= 1) {
        s  += __shfl_down(s,  off, 64);
        s2 += __shfl_down(s2, off, 64);
    }
    if ((tid & 63) == 0) { ss[tid >> 6] = s; ss2[tid >> 6] = s2; }
    __syncthreads();
    float tot  = ss[0] + ss[1] + ss[2] + ss[3];
    float tot2 = ss2[0] + ss2[1] + ss2[2] + ss2[3];
    float mu   = tot * (1.f / ND);
    float var  = fmaf(tot2, 1.f / ND, -mu * mu);
    float rstd = rsqrtf(var + 1e-5f);
    float4 wv = ((const float4*)gw)[tid];
    float4 bv = ((const float4*)gb)[tid];
    ushort4 o;
    o.x = f2bf(fmaf((v.x - mu) * rstd, wv.x, bv.x));
    o.y = f2bf(fmaf((v.y - mu) * rstd, wv.y, bv.y));
    o.z = f2bf(fmaf((v.z - mu) * rstd, wv.z, bv.z));
    o.w = f2bf(fmaf((v.w - mu) * rstd, wv.w, bv.w));
    ((ushort4*)(xn + row * ND))[tid] = o;
}

// ================= 256x256 8-phase pipelined MFMA GEMM =================
// C[M,N] = A[M,K] @ B[N,K]^T, bf16 in, f32 acc.
// EPI 1: f32 (acc+resid) nontemporal store.
// EPI 2: fused mamba epilogue: x-half tiles (n0<2048) -> causal conv(4)+silu
//        via wave-private LDS [c][t], store bf16 xact; z-half -> silu, store
//        compact bf16 zs (nontemporal).

#define BARRIER __builtin_amdgcn_s_barrier()
#define LGKM0  asm volatile("s_waitcnt lgkmcnt(0)" ::: "memory")
#define VMCNT6 asm volatile("s_waitcnt vmcnt(6)" ::: "memory")
#define VMCNT0 asm volatile("s_waitcnt vmcnt(0)" ::: "memory")
#define NOWAIT ((void)0)
#define PRIO1  __builtin_amdgcn_s_setprio(1)
#define PRIO0  __builtin_amdgcn_s_setprio(0)

#define STG_A(t, kp) {                                                        \
    gl_lds16(gA0 + (size_t)(t) * 64 + (kp) * 32,                              \
             lA + (((t) & 1) << 15) + ((kp) << 14));                          \
    gl_lds16(gA1 + (size_t)(t) * 64 + (kp) * 32,                              \
             lA + (((t) & 1) << 15) + ((kp) << 14) + 8192); }
#define STG_B(t, kp) {                                                        \
    gl_lds16(gB0 + (size_t)(t) * 64 + (kp) * 32,                              \
             lB + (((t) & 1) << 15) + ((kp) << 14));                          \
    gl_lds16(gB1 + (size_t)(t) * 64 + (kp) * 32,                              \
             lB + (((t) & 1) << 15) + ((kp) << 14) + 8192); }

#define RD_A(dst, mh, kp) { _Pragma("unroll")                                 \
    for (int mi = 0; mi < 4; ++mi)                                            \
        dst[mi] = *(const bf16x8*)(aRd + bo + (kp) * 16384 + (mh) * 4096 + mi * 1024); }
#define RD_B(dst, kp) { _Pragma("unroll")                                     \
    for (int ni = 0; ni < 4; ++ni)                                            \
        dst[ni] = *(const bf16x8*)(bRd + bo + (kp) * 16384 + ni * 1024); }

#define MM(mh, AV, BV) { _Pragma("unroll")                                    \
    for (int mi = 0; mi < 4; ++mi) { _Pragma("unroll")                        \
        for (int ni = 0; ni < 4; ++ni)                                        \
            acc[(mh) * 4 + mi][ni] = __builtin_amdgcn_mfma_f32_16x16x32_bf16( \
                AV[mi], BV[ni], acc[(mh) * 4 + mi][ni], 0, 0, 0); } }

#define TILE(t, DO_AP1, DO_T2, W) {                                           \
    const int bo = ((t) & 1) << 15;                                           \
    RD_A(aK0, 0, 0); RD_B(bK0, 0);                                            \
    if (DO_AP1) STG_A((t) + 1, 1);                                            \
    BARRIER; LGKM0; PRIO1; MM(0, aK0, bK0); PRIO0; BARRIER;                   \
    RD_A(aK1, 0, 1); RD_B(bK1, 1);                                            \
    if (DO_T2) STG_B((t) + 2, 0);                                             \
    BARRIER; LGKM0; PRIO1; MM(0, aK1, bK1); PRIO0; BARRIER;                   \
    RD_A(aK0, 1, 0);                                                          \
    if (DO_T2) STG_B((t) + 2, 1);                                             \
    BARRIER; LGKM0; PRIO1; MM(1, aK0, bK0); PRIO0; BARRIER;                   \
    RD_A(aK1, 1, 1);                                                          \
    if (DO_T2) STG_A((t) + 2, 0);                                             \
    BARRIER; LGKM0; PRIO1; MM(1, aK1, bK1); PRIO0;                            \
    W;                                                                        \
    BARRIER; }

template <int K, int EPI>
__global__ __launch_bounds__(512, 2)
void gemm256(const unsigned short* __restrict__ A,
             const unsigned short* __restrict__ B,
             int N, void* __restrict__ outp, const float* __restrict__ resid,
             const float* __restrict__ cw, const float* __restrict__ cb,
             unsigned short* __restrict__ out2) {
    constexpr int NT = K / 64;
    static_assert(NT >= 3, "need >=3 K-tiles");
    __shared__ __align__(16) char smem[131072];

    const int tid  = threadIdx.x;
    const int lane = tid & 63;
    const int wid  = tid >> 6;
    const int lrow = lane & 15;
    const int kq   = lane >> 4;
    const int wmi  = wid >> 2;
    const int wni  = wid & 3;

    const int gx  = gridDim.x;
    const int nwg = gx * gridDim.y;
    const int lin = blockIdx.y * gx + blockIdx.x;
    const int id2 = (lin & 7) * (nwg >> 3) + (lin >> 3);
    const int bm  = id2 % gx;
    const int bn  = id2 / gx;

    const size_t m0 = (size_t)bm * 256;
    const size_t n0 = (size_t)bn * 256;

    const int fr = (lrow >> 1) & 3;
    const char* aRd = smem +          (wmi * 128 + lrow) * 64 + ((kq ^ fr) << 4);
    const char* bRd = smem + 65536 + (wni * 64  + lrow) * 64 + ((kq ^ fr) << 4);

    const int srow = wid * 16 + (lane >> 2);
    const int scol = (((lane & 3) ^ ((lane >> 3) & 3)) << 3);
    const unsigned short* gA0 = A + (m0 + srow) * K + scol;
    const unsigned short* gA1 = A + (m0 + 128 + srow) * K + scol;
    const unsigned short* gB0 = B + (n0 + srow) * K + scol;
    const unsigned short* gB1 = B + (n0 + 128 + srow) * K + scol;
    char* lA = smem + wid * 1024;
    char* lB = smem + 65536 + wid * 1024;

    f32x4 acc[8][4];
    #pragma unroll
    for (int i = 0; i < 8; ++i)
        #pragma unroll
        for (int j = 0; j < 4; ++j) acc[i][j] = (f32x4){0.f, 0.f, 0.f, 0.f};

    bf16x8 aK0[4], aK1[4], bK0[4], bK1[4];

    STG_B(0, 0); STG_B(0, 1); STG_A(0, 0); STG_A(0, 1);
    STG_B(1, 0); STG_B(1, 1); STG_A(1, 0);
    VMCNT6;
    BARRIER;

    int t = 0;
    #pragma unroll 2
    for (; t < NT - 2; ++t) { TILE(t, 1, 1, VMCNT6); }
    TILE((NT - 2), 1, 0, VMCNT0);
    TILE((NT - 1), 0, 0, NOWAIT);

    if (EPI == 1) {
        #pragma unroll
        for (int mi = 0; mi < 8; ++mi)
            #pragma unroll
            for (int ni = 0; ni < 4; ++ni)
                #pragma unroll
                for (int r = 0; r < 4; ++r) {
                    size_t row = m0 + wmi * 128 + mi * 16 + kq * 4 + r;
                    size_t col = n0 + wni * 64 + ni * 16 + lrow;
                    size_t idx = row * (size_t)N + col;
                    float v = acc[mi][ni][r] + __builtin_nontemporal_load(&resid[idx]);
                    __builtin_nontemporal_store(v, &((float*)outp)[idx]);
                }
    } else {
        // EPI == 2: fused mamba epilogue
        BARRIER;                                   // all waves done with smem
        if (n0 < 2048) {
            // ---- causal conv(4) + silu, wave-private LDS [c][t] bf16 swz ----
            char* wb = smem + wid * 16384;
            #pragma unroll
            for (int mi = 0; mi < 8; ++mi)
                #pragma unroll
                for (int ni = 0; ni < 4; ++ni) {
                    int cl = ni * 16 + lrow;       // local channel row 0..63
                    int slot = mi * 2 + (kq >> 1); // t-slot 0..15
                    ushort4 pk;
                    pk.x = f2bf(acc[mi][ni][0]); pk.y = f2bf(acc[mi][ni][1]);
                    pk.z = f2bf(acc[mi][ni][2]); pk.w = f2bf(acc[mi][ni][3]);
                    *(ushort4*)(wb + cl * 256 +
                                (((slot ^ lrow) << 4) | ((kq & 1) << 3))) = pk;
                }
            LGKM0;
            __builtin_amdgcn_sched_barrier(0);
            const int ch = (int)n0 + wni * 64 + lane;   // global channel
            float4 wv = ((const float4*)cw)[ch];
            float bias = cb[ch];
            float x0 = 0.f, x1 = 0.f, x2 = 0.f;
            unsigned short* po = (unsigned short*)outp + (m0 + wmi * 128) * NDI + ch;
            const char* rb = wb + lane * 256;
            const int cx = lane & 15;
            for (int s = 0; s < 16; ++s) {
                bf16x8 v = *(const bf16x8*)(rb + ((s ^ cx) << 4));
                #pragma unroll
                for (int j = 0; j < 8; ++j) {
                    float x3 = bf2f((unsigned short)v[j]);
                    float vv = fmaf(x3, wv.w, fmaf(x2, wv.z,
                               fmaf(x1, wv.y, fmaf(x0, wv.x, bias))));
                    float sg = vv * __builtin_amdgcn_rcpf(1.f + __expf(-vv));
                    po[(size_t)(s * 8 + j) * NDI] = f2bf(sg);
                    x0 = x1; x1 = x2; x2 = x3;
                }
            }
        } else {
            // ---- z-half: zs = silu(acc) compact bf16, nontemporal ----
            #pragma unroll
            for (int mi = 0; mi < 8; ++mi)
                #pragma unroll
                for (int ni = 0; ni < 4; ++ni)
                    #pragma unroll
                    for (int r = 0; r < 4; ++r) {
                        size_t row = m0 + wmi * 128 + mi * 16 + kq * 4 + r;
                        size_t col = (n0 - 2048) + wni * 64 + ni * 16 + lrow;
                        float v = acc[mi][ni][r];
                        float sg = v * __builtin_amdgcn_rcpf(1.f + __expf(-v));
                        __builtin_nontemporal_store(f2bf(sg), &out2[row * 2048 + col]);
                    }
        }
    }
}

// ---------------- GEMM2: x_ssm[25600,80] = x_act[25600,2048] @ Wx[80,2048]^T ----------------
__global__ __launch_bounds__(256, 2)
void gemm2_kernel(const unsigned short* __restrict__ A,
                  const unsigned short* __restrict__ B,
                  float* __restrict__ out) {
    __shared__ __align__(16) unsigned short As[64 * 32];
    __shared__ __align__(16) unsigned short Bs[80 * 32];
    const int tid  = threadIdx.x;
    const int bm   = blockIdx.x;
    const int wid  = tid >> 6;
    const int lane = tid & 63;
    const int lrow = lane & 15;
    const int kq   = lane >> 4;

    f32x4 acc[5];
    #pragma unroll
    for (int i = 0; i < 5; i++) acc[i] = (f32x4){0.f, 0.f, 0.f, 0.f};

    const int r1 = tid >> 2;
    const int c8 = (tid & 3) << 3;
    const unsigned short* gA1 = A + ((size_t)bm * 64 + r1) * NDI + c8;
    const unsigned short* gB1 = B + (size_t)r1 * NDI + c8;
    const unsigned short* gB2 = B + (size_t)(64 + r1) * NDI + c8;
    char* lA1 = (char*)As + wid * 1024;
    char* lB1 = (char*)Bs + wid * 1024;
    char* lB2 = (char*)Bs + 4096;

    for (int kt = 0; kt < NDI; kt += 32) {
        __syncthreads();
        gl_lds16(gA1, lA1);
        gl_lds16(gB1, lB1);
        if (tid < 64) gl_lds16(gB2, lB2);
        gA1 += 32; gB1 += 32; gB2 += 32;
        __syncthreads();
        bf16x8 af = *(const bf16x8*)&As[(wid * 16 + lrow) * 32 + kq * 8];
        #pragma unroll
        for (int ni = 0; ni < 5; ni++) {
            bf16x8 bfr = *(const bf16x8*)&Bs[(ni * 16 + lrow) * 32 + kq * 8];
            acc[ni] = __builtin_amdgcn_mfma_f32_16x16x32_bf16(af, bfr, acc[ni], 0, 0, 0);
        }
    }
    #pragma unroll
    for (int ni = 0; ni < 5; ni++)
        #pragma unroll
        for (int r = 0; r < 4; r++) {
            size_t row = (size_t)bm * 64 + wid * 16 + kq * 4 + r;
            int col = ni * 16 + lrow;
            out[row * 80 + col] = acc[ni][r];
        }
}

// ================= SSD chunked selective scan =================
// Per block: (b, 256-d slice). 4 chunks of T=32 steps, h0 carried in LDS.
// y[t,d] = Einv[t,d]*( C@h0 + Gmask@P )[t,d],  P[s,d]=xa*exp(L'[s,d]),
// h0' = Einv[31,d]*(h0 + B^T@P).  G[t,s]=sum_n C[t,n]B[s,n] shared over d.
// Output g = y*zs written in-place over x_act (bf16); zs = silu(z) precomputed.
__global__ __launch_bounds__(256, 2)
void ssd_kernel(const float* __restrict__ xssm,          // [25600,80]: [dr | B(32) | C(32) | pad]
                unsigned short* xact_g,                   // in: x_act, out: g (bf16, in-place)
                const unsigned short* __restrict__ zs,    // silu(z) bf16 [25600,2048]
                const float* __restrict__ dtW,
                const float* __restrict__ dtb,
                const float* __restrict__ eb,             // [25600] f32
                const float* __restrict__ es_p) {
    __shared__ float sDR[32], sDE[32];
    __shared__ __align__(16) unsigned short sC[32][32];    // [t][n]
    __shared__ __align__(16) unsigned short sB[32][32];    // [s][n]
    __shared__ __align__(16) unsigned short sBt[32][32];   // [n][s]
    __shared__ __align__(16) unsigned short sG[32][32];    // [t][s] swz
    __shared__ __align__(16) unsigned short sP[256][32];   // [dloc][s] swz (wave-local)
    __shared__ __align__(16) float          sE[256][32];   // [dloc][t] swz, Einv=exp(-L')
    __shared__ __align__(16) unsigned short sH[256][32];   // [dloc][n] h0 bf16

    const int tid  = threadIdx.x;
    const int b    = blockIdx.y;
    const int d0   = blockIdx.x * 256;
    const int lane = tid & 63;
    const int wid  = tid >> 6;
    const int lrow = lane & 15;
    const int kq   = lane >> 4;
    const int wd0  = wid * 64;

    const float w  = dtW[d0 + tid];
    const float bb = dtb[d0 + tid];
    const float es = es_p[0];

    // h0 = 0
    for (int i = tid; i < 256 * 32; i += 256) ((unsigned short*)sH)[i] = 0;

    #pragma unroll 1
    for (int c = 0; c < 4; ++c) {
        __syncthreads();                         // protect staging vs prev readers
        // ---- stage xssm chunk slice + emotion bias ----
        {
            const float* src = xssm + ((size_t)b * 128 + c * 32) * 80;
            for (int i = tid; i < 2560; i += 256) {
                int t = i / 80, col = i - t * 80;
                float v = src[i];
                if (col == 0) sDR[t] = v;
                else if (col < 33) {
                    unsigned short bv = f2bf(v);
                    sB[t][col - 1] = bv;
                    sBt[col - 1][t] = bv;
                } else if (col < 65) sC[t][col - 33] = f2bf(v);
            }
            if (tid < 32) sDE[tid] = es * eb[b * 128 + c * 32 + tid];
        }
        __syncthreads();

        // ---- G = C B^T with causal mask (wave wid -> fragment wid) ----
        {
            int mi = wid >> 1, ni = wid & 1;
            bf16x8 af = *(const bf16x8*)&sC[mi * 16 + lrow][kq * 8];
            bf16x8 bf = *(const bf16x8*)&sB[ni * 16 + lrow][kq * 8];
            f32x4 z4 = (f32x4){0.f, 0.f, 0.f, 0.f};
            f32x4 g = __builtin_amdgcn_mfma_f32_16x16x32_bf16(af, bf, z4, 0, 0, 0);
            #pragma unroll
            for (int r = 0; r < 4; ++r) {
                int t = mi * 16 + kq * 4 + r, s = ni * 16 + lrow;
                float val = (s <= t) ? g[r] : 0.f;
                *(unsigned short*)((char*)sG + t * 64 +
                    ((((s >> 3) ^ (t & 3)) << 4) | ((s & 7) << 1))) = f2bf(val);
            }
        }

        // ---- P/E gen: serial 32-step prefix per thread (dloc = tid) ----
        {
            const unsigned short* pxa =
                xact_g + ((size_t)b * 128 + c * 32) * 2048 + d0 + tid;
            float L = 0.f;
            for (int t8 = 0; t8 < 4; ++t8) {
                bf16x8 pv;
                #pragma unroll
                for (int j = 0; j < 8; ++j) {
                    int t = t8 * 8 + j;
                    float raw = fmaf(sDR[t], w, bb);
                    float sp  = (raw > 20.f) ? raw : __logf(1.f + __expf(raw));
                    float delta = fmaxf(sp + sDE[t], 1e-4f);
                    L += delta;
                    float xa = bf2f(pxa[(size_t)t * 2048]);
                    pv[j] = (short)f2bf(xa * __expf(L));
                    *(float*)((char*)sE + tid * 128 +
                        ((((t >> 2) ^ (tid & 7)) << 4) | ((t & 3) << 2))) = __expf(-L);
                }
                *(bf16x8*)((char*)sP + tid * 64 + (((t8 ^ (tid & 3)) << 4))) = pv;
            }
        }
        __syncthreads();

        // ---- MFMA phase: acc = C@h0 + Gmask@P ; racc = B^T@P ----
        f32x4 acc[2][4], racc[2][4];
        bf16x8 cfrag[2], gfrag[2], btfrag[2], hfrag[4], pfrag[4];
        #pragma unroll
        for (int mi = 0; mi < 2; ++mi) {
            int tr = mi * 16 + lrow;
            cfrag[mi]  = *(const bf16x8*)&sC[tr][kq * 8];
            gfrag[mi]  = *(const bf16x8*)((const char*)sG + tr * 64 +
                                          (((kq ^ (tr & 3)) << 4)));
            btfrag[mi] = *(const bf16x8*)&sBt[tr][kq * 8];
        }
        #pragma unroll
        for (int ni = 0; ni < 4; ++ni) {
            int dc = wd0 + ni * 16 + lrow;
            hfrag[ni] = *(const bf16x8*)&sH[dc][kq * 8];
            pfrag[ni] = *(const bf16x8*)((const char*)sP + dc * 64 +
                                         (((kq ^ (dc & 3)) << 4)));
        }
        #pragma unroll
        for (int mi = 0; mi < 2; ++mi)
            #pragma unroll
            for (int ni = 0; ni < 4; ++ni) {
                f32x4 z4 = (f32x4){0.f, 0.f, 0.f, 0.f};
                acc[mi][ni] = __builtin_amdgcn_mfma_f32_16x16x32_bf16(
                    cfrag[mi], hfrag[ni], z4, 0, 0, 0);
                acc[mi][ni] = __builtin_amdgcn_mfma_f32_16x16x32_bf16(
                    gfrag[mi], pfrag[ni], acc[mi][ni], 0, 0, 0);
                racc[mi][ni] = __builtin_amdgcn_mfma_f32_16x16x32_bf16(
                    btfrag[mi], pfrag[ni], z4, 0, 0, 0);
            }

        // ---- epilogue: g = Einv*acc * zs, in-place over x_act ----
        #pragma unroll
        for (int mi = 0; mi < 2; ++mi)
            #pragma unroll
            for (int ni = 0; ni < 4; ++ni) {
                int dc = wd0 + ni * 16 + lrow;
                f32x4 ev = *(const f32x4*)((const char*)sE + dc * 128 +
                                           ((((mi * 4 + kq) ^ (dc & 7)) << 4)));
                size_t rowg = (size_t)b * 128 + c * 32 + mi * 16 + kq * 4;
                #pragma unroll
                for (int r = 0; r < 4; ++r) {
                    size_t gi = (rowg + r) * 2048 + d0 + dc;
                    float y  = acc[mi][ni][r] * ev[r];
                    xact_g[gi] = f2bf(y * bf2f(zs[gi]));
                }
            }

        // ---- h0 update (wave-local d range): h0' = Einv[31]*(h0 + R) ----
        #pragma unroll
        for (int ni = 0; ni < 4; ++ni) {
            int dc = wd0 + ni * 16 + lrow;
            float e31 = *(const float*)((const char*)sE + dc * 128 +
                                        (((7 ^ (dc & 7)) << 4) | 12));
            #pragma unroll
            for (int mi = 0; mi < 2; ++mi)
                #pragma unroll
                for (int r = 0; r < 4; ++r) {
                    int n = mi * 16 + kq * 4 + r;
                    float h = bf2f(sH[dc][n]) + racc[mi][ni][r];
                    sH[dc][n] = f2bf(e31 * h);
                }
        }
    }
}

// ---------------- launch ----------------
extern "C" void kernel_launch(void* const* d_in, const int* in_sizes, int n_in,
                              void* d_out, int out_size, void* d_ws, size_t ws_size,
                              hipStream_t stream) {
    const float* x   = (const float*)d_in[0];
    const float* eb  = (const float*)d_in[1];
    const float* nw  = (const float*)d_in[2];
    const float* nb  = (const float*)d_in[3];
    const float* Wi  = (const float*)d_in[4];
    const float* cw  = (const float*)d_in[5];
    const float* cb  = (const float*)d_in[6];
    const float* Wx  = (const float*)d_in[7];
    const float* dtW = (const float*)d_in[8];
    const float* dtb = (const float*)d_in[9];
    const float* Wo  = (const float*)d_in[10];
    const float* es  = (const float*)d_in[11];
    float* out = (float*)d_out;                     // FLOAT32 output

    // workspace layout (bytes, 256-aligned)
    char* ws = (char*)d_ws;
    unsigned short* wi_b   = (unsigned short*)(ws + 0);            //   8,388,608
    unsigned short* wo_b   = (unsigned short*)(ws + 8388608);      //   4,194,304
    unsigned short* wx_b   = (unsigned short*)(ws + 12582912);     //     327,680
    unsigned short* zs_b   = (unsigned short*)(ws + 12910592);     // 104,857,600 silu(z)
    unsigned short* xn_b   = (unsigned short*)(ws + 117768192);    //  52,428,800
    unsigned short* xact_b = (unsigned short*)(ws + 170196992);    // 104,857,600
    float*          xssm   = (float*)(ws + 275054592);             //   8,192,000 -> 283,246,592
    if (ws_size < (size_t)283246592) return;

    // 1. weights -> bf16
    cvt_kernel<<<(2 * NDI * ND + 255) / 256, 256, 0, stream>>>(Wi, wi_b, 2 * NDI * ND);
    cvt_kernel<<<(ND * NDI + 255) / 256, 256, 0, stream>>>(Wo, wo_b, ND * NDI);
    padwx_kernel<<<(80 * NDI) / 256, 256, 0, stream>>>(Wx, wx_b);

    // 2. LayerNorm -> xn (bf16)
    ln_kernel<<<NROWS, 256, 0, stream>>>(x, nw, nb, xn_b);

    // 3. GEMM1 fused: x_act = silu(conv(xn @ Wi^T[:,0:2048])), zs = silu(z-half)
    gemm256<ND, 2><<<dim3(NROWS / 256, (2 * NDI) / 256), 512, 0, stream>>>(
        xn_b, wi_b, 2 * NDI, xact_b, nullptr, cw, cb, zs_b);

    // 4. GEMM2: x_ssm = x_act @ Wx^T  [25600,80] f32
    gemm2_kernel<<<NROWS / 64, 256, 0, stream>>>(xact_b, wx_b, xssm);

    // 5. SSD chunked scan + gating (g overwrites x_act)
    ssd_kernel<<<dim3(NDI / 256, NBN), 256, 0, stream>>>(xssm, xact_b, zs_b, dtW, dtb, eb, es);

    // 6. GEMM3: out = g @ Wo^T + residual  (f32 nontemporal store)
    gemm256<NDI, 1><<<dim3(NROWS / 256, ND / 256), 512, 0, stream>>>(
        xact_b, wo_b, ND, out, x, nullptr, nullptr, nullptr);
}

// Round 5
// 811.269 us; speedup vs baseline: 1.1898x; 1.0686x over previous
//
#include <hip/hip_runtime.h>
#include <cstdint>
#include <cstddef>

// Problem constants
#define NBN   200
#define NS    128
#define ND    1024
#define NDI   2048
#define NST   32
#define NROWS (NBN * NS)          // 25600

typedef __attribute__((ext_vector_type(8))) short bf16x8;   // 8 bf16 = 4 VGPRs
typedef __attribute__((ext_vector_type(4))) float f32x4;

__device__ __forceinline__ unsigned short f2bf(float f) {
    unsigned int u = __float_as_uint(f);
    u += 0x7fffu + ((u >> 16) & 1u);          // round-to-nearest-even
    return (unsigned short)(u >> 16);
}
__device__ __forceinline__ float bf2f(unsigned short h) {
    return __uint_as_float(((unsigned int)h) << 16);
}

// async global->LDS, 16B per lane. LDS dest = wave-uniform base + lane*16.
__device__ __forceinline__ void gl_lds16(const void* g, void* l) {
    typedef __attribute__((address_space(1))) const unsigned int* gp_t;
    typedef __attribute__((address_space(3))) unsigned int* lp_t;
    __builtin_amdgcn_global_load_lds((gp_t)(uintptr_t)g,
                                     (lp_t)(unsigned int)(uintptr_t)l, 16, 0, 0);
}

// ---------------- weight prep: f32 -> bf16 ----------------
__global__ __launch_bounds__(256) void cvt_kernel(const float* __restrict__ src,
                                                  unsigned short* __restrict__ dst, int n) {
    int i = blockIdx.x * 256 + threadIdx.x;
    if (i < n) dst[i] = f2bf(src[i]);
}

// x_proj_W f32 [65,2048] -> padded bf16 [80,2048] (pad rows zero)
__global__ __launch_bounds__(256) void padwx_kernel(const float* __restrict__ src,
                                                    unsigned short* __restrict__ dst) {
    int i = blockIdx.x * 256 + threadIdx.x;   // 80*2048
    int r = i >> 11;
    dst[i] = (r < 65) ? f2bf(src[i]) : (unsigned short)0;
}

// ---------------- LayerNorm: x[row,1024] f32 -> xn bf16 ----------------
__global__ __launch_bounds__(256) void ln_kernel(const float* __restrict__ x,
                                                 const float* __restrict__ gw,
                                                 const float* __restrict__ gb,
                                                 unsigned short* __restrict__ xn) {
    __shared__ float ss[4], ss2[4];
    size_t row = blockIdx.x;
    int tid = threadIdx.x;
    const float4* px = (const float4*)(x + row * ND);
    float4 v = px[tid];
    float s  = v.x + v.y + v.z + v.w;
    float s2 = fmaf(v.x, v.x, fmaf(v.y, v.y, fmaf(v.z, v.z, v.w * v.w)));
    #pragma unroll
    for (int off = 32; off > 0; off >>= 1) {
        s  += __shfl_down(s,  off, 64);
        s2 += __shfl_down(s2, off, 64);
    }
    if ((tid & 63) == 0) { ss[tid >> 6] = s; ss2[tid >> 6] = s2; }
    __syncthreads();
    float tot  = ss[0] + ss[1] + ss[2] + ss[3];
    float tot2 = ss2[0] + ss2[1] + ss2[2] + ss2[3];
    float mu   = tot * (1.f / ND);
    float var  = fmaf(tot2, 1.f / ND, -mu * mu);
    float rstd = rsqrtf(var + 1e-5f);
    float4 wv = ((const float4*)gw)[tid];
    float4 bv = ((const float4*)gb)[tid];
    ushort4 o;
    o.x = f2bf(fmaf((v.x - mu) * rstd, wv.x, bv.x));
    o.y = f2bf(fmaf((v.y - mu) * rstd, wv.y, bv.y));
    o.z = f2bf(fmaf((v.z - mu) * rstd, wv.z, bv.z));
    o.w = f2bf(fmaf((v.w - mu) * rstd, wv.w, bv.w));
    ((ushort4*)(xn + row * ND))[tid] = o;
}

// ================= 256x256 8-phase pipelined MFMA GEMM =================
// C[M,N] = A[M,K] @ B[N,K]^T, bf16 in, f32 acc.
// EPI 1: f32 (acc+resid) nontemporal store.
// EPI 2: fused mamba epilogue: x-half tiles (n0<2048) -> causal conv(4)+silu
//        via wave-private LDS [c][t], store bf16 xact; z-half -> silu, store
//        compact bf16 zs (regular stores: zs is re-read by ssd, keep in LLC).

#define BARRIER __builtin_amdgcn_s_barrier()
#define LGKM0  asm volatile("s_waitcnt lgkmcnt(0)" ::: "memory")
#define VMCNT6 asm volatile("s_waitcnt vmcnt(6)" ::: "memory")
#define VMCNT0 asm volatile("s_waitcnt vmcnt(0)" ::: "memory")
#define NOWAIT ((void)0)
#define PRIO1  __builtin_amdgcn_s_setprio(1)
#define PRIO0  __builtin_amdgcn_s_setprio(0)

#define STG_A(t, kp) {                                                        \
    gl_lds16(gA0 + (size_t)(t) * 64 + (kp) * 32,                              \
             lA + (((t) & 1) << 15) + ((kp) << 14));                          \
    gl_lds16(gA1 + (size_t)(t) * 64 + (kp) * 32,                              \
             lA + (((t) & 1) << 15) + ((kp) << 14) + 8192); }
#define STG_B(t, kp) {                                                        \
    gl_lds16(gB0 + (size_t)(t) * 64 + (kp) * 32,                              \
             lB + (((t) & 1) << 15) + ((kp) << 14));                          \
    gl_lds16(gB1 + (size_t)(t) * 64 + (kp) * 32,                              \
             lB + (((t) & 1) << 15) + ((kp) << 14) + 8192); }

#define RD_A(dst, mh, kp) { _Pragma("unroll")                                 \
    for (int mi = 0; mi < 4; ++mi)                                            \
        dst[mi] = *(const bf16x8*)(aRd + bo + (kp) * 16384 + (mh) * 4096 + mi * 1024); }
#define RD_B(dst, kp) { _Pragma("unroll")                                     \
    for (int ni = 0; ni < 4; ++ni)                                            \
        dst[ni] = *(const bf16x8*)(bRd + bo + (kp) * 16384 + ni * 1024); }

#define MM(mh, AV, BV) { _Pragma("unroll")                                    \
    for (int mi = 0; mi < 4; ++mi) { _Pragma("unroll")                        \
        for (int ni = 0; ni < 4; ++ni)                                        \
            acc[(mh) * 4 + mi][ni] = __builtin_amdgcn_mfma_f32_16x16x32_bf16( \
                AV[mi], BV[ni], acc[(mh) * 4 + mi][ni], 0, 0, 0); } }

#define TILE(t, DO_AP1, DO_T2, W) {                                           \
    const int bo = ((t) & 1) << 15;                                           \
    RD_A(aK0, 0, 0); RD_B(bK0, 0);                                            \
    if (DO_AP1) STG_A((t) + 1, 1);                                            \
    BARRIER; LGKM0; PRIO1; MM(0, aK0, bK0); PRIO0; BARRIER;                   \
    RD_A(aK1, 0, 1); RD_B(bK1, 1);                                            \
    if (DO_T2) STG_B((t) + 2, 0);                                             \
    BARRIER; LGKM0; PRIO1; MM(0, aK1, bK1); PRIO0; BARRIER;                   \
    RD_A(aK0, 1, 0);                                                          \
    if (DO_T2) STG_B((t) + 2, 1);                                             \
    BARRIER; LGKM0; PRIO1; MM(1, aK0, bK0); PRIO0; BARRIER;                   \
    RD_A(aK1, 1, 1);                                                          \
    if (DO_T2) STG_A((t) + 2, 0);                                             \
    BARRIER; LGKM0; PRIO1; MM(1, aK1, bK1); PRIO0;                            \
    W;                                                                        \
    BARRIER; }

template <int K, int EPI>
__global__ __launch_bounds__(512, 2)
void gemm256(const unsigned short* __restrict__ A,
             const unsigned short* __restrict__ B,
             int N, void* __restrict__ outp, const float* __restrict__ resid,
             const float* __restrict__ cw, const float* __restrict__ cb,
             unsigned short* __restrict__ out2) {
    constexpr int NT = K / 64;
    static_assert(NT >= 3, "need >=3 K-tiles");
    __shared__ __align__(16) char smem[131072];

    const int tid  = threadIdx.x;
    const int lane = tid & 63;
    const int wid  = tid >> 6;
    const int lrow = lane & 15;
    const int kq   = lane >> 4;
    const int wmi  = wid >> 2;
    const int wni  = wid & 3;

    // T1: bijective XCD swizzle, bn-minor within each XCD chunk:
    //  - x-half / z-half tiles interleave on every XCD (balanced conv tails)
    //  - A-tile (0.5 MB) stays L2-resident across the bn sweep of its bm row
    const int gx  = gridDim.x;
    const int gy  = gridDim.y;
    const int nwg = gx * gy;
    const int lin = blockIdx.y * gx + blockIdx.x;
    const int id2 = (lin & 7) * (nwg >> 3) + (lin >> 3);
    const int bn  = id2 % gy;
    const int bm  = id2 / gy;

    const size_t m0 = (size_t)bm * 256;
    const size_t n0 = (size_t)bn * 256;

    const int fr = (lrow >> 1) & 3;
    const char* aRd = smem +          (wmi * 128 + lrow) * 64 + ((kq ^ fr) << 4);
    const char* bRd = smem + 65536 + (wni * 64  + lrow) * 64 + ((kq ^ fr) << 4);

    const int srow = wid * 16 + (lane >> 2);
    const int scol = (((lane & 3) ^ ((lane >> 3) & 3)) << 3);
    const unsigned short* gA0 = A + (m0 + srow) * K + scol;
    const unsigned short* gA1 = A + (m0 + 128 + srow) * K + scol;
    const unsigned short* gB0 = B + (n0 + srow) * K + scol;
    const unsigned short* gB1 = B + (n0 + 128 + srow) * K + scol;
    char* lA = smem + wid * 1024;
    char* lB = smem + 65536 + wid * 1024;

    f32x4 acc[8][4];
    #pragma unroll
    for (int i = 0; i < 8; ++i)
        #pragma unroll
        for (int j = 0; j < 4; ++j) acc[i][j] = (f32x4){0.f, 0.f, 0.f, 0.f};

    bf16x8 aK0[4], aK1[4], bK0[4], bK1[4];

    STG_B(0, 0); STG_B(0, 1); STG_A(0, 0); STG_A(0, 1);
    STG_B(1, 0); STG_B(1, 1); STG_A(1, 0);
    VMCNT6;
    BARRIER;

    int t = 0;
    #pragma unroll 2
    for (; t < NT - 2; ++t) { TILE(t, 1, 1, VMCNT6); }
    TILE((NT - 2), 1, 0, VMCNT0);
    TILE((NT - 1), 0, 0, NOWAIT);

    if (EPI == 1) {
        #pragma unroll
        for (int mi = 0; mi < 8; ++mi)
            #pragma unroll
            for (int ni = 0; ni < 4; ++ni)
                #pragma unroll
                for (int r = 0; r < 4; ++r) {
                    size_t row = m0 + wmi * 128 + mi * 16 + kq * 4 + r;
                    size_t col = n0 + wni * 64 + ni * 16 + lrow;
                    size_t idx = row * (size_t)N + col;
                    float v = acc[mi][ni][r] + __builtin_nontemporal_load(&resid[idx]);
                    __builtin_nontemporal_store(v, &((float*)outp)[idx]);
                }
    } else {
        // EPI == 2: fused mamba epilogue
        BARRIER;                                   // all waves done with smem
        if (n0 < 2048) {
            // ---- causal conv(4) + silu, wave-private LDS [c][t] bf16 swz ----
            char* wb = smem + wid * 16384;
            #pragma unroll
            for (int mi = 0; mi < 8; ++mi)
                #pragma unroll
                for (int ni = 0; ni < 4; ++ni) {
                    int cl = ni * 16 + lrow;       // local channel row 0..63
                    int slot = mi * 2 + (kq >> 1); // t-slot 0..15
                    ushort4 pk;
                    pk.x = f2bf(acc[mi][ni][0]); pk.y = f2bf(acc[mi][ni][1]);
                    pk.z = f2bf(acc[mi][ni][2]); pk.w = f2bf(acc[mi][ni][3]);
                    *(ushort4*)(wb + cl * 256 +
                                (((slot ^ lrow) << 4) | ((kq & 1) << 3))) = pk;
                }
            LGKM0;
            __builtin_amdgcn_sched_barrier(0);
            const int ch = (int)n0 + wni * 64 + lane;   // global channel
            float4 wv = ((const float4*)cw)[ch];
            float bias = cb[ch];
            float x0 = 0.f, x1 = 0.f, x2 = 0.f;
            unsigned short* po = (unsigned short*)outp + (m0 + wmi * 128) * NDI + ch;
            const char* rb = wb + lane * 256;
            const int cx = lane & 15;
            for (int s = 0; s < 16; ++s) {
                bf16x8 v = *(const bf16x8*)(rb + ((s ^ cx) << 4));
                #pragma unroll
                for (int j = 0; j < 8; ++j) {
                    float x3 = bf2f((unsigned short)v[j]);
                    float vv = fmaf(x3, wv.w, fmaf(x2, wv.z,
                               fmaf(x1, wv.y, fmaf(x0, wv.x, bias))));
                    float sg = vv * __builtin_amdgcn_rcpf(1.f + __expf(-vv));
                    po[(size_t)(s * 8 + j) * NDI] = f2bf(sg);
                    x0 = x1; x1 = x2; x2 = x3;
                }
            }
        } else {
            // ---- z-half: zs = silu(acc) compact bf16 (regular stores) ----
            #pragma unroll
            for (int mi = 0; mi < 8; ++mi)
                #pragma unroll
                for (int ni = 0; ni < 4; ++ni)
                    #pragma unroll
                    for (int r = 0; r < 4; ++r) {
                        size_t row = m0 + wmi * 128 + mi * 16 + kq * 4 + r;
                        size_t col = (n0 - 2048) + wni * 64 + ni * 16 + lrow;
                        float v = acc[mi][ni][r];
                        float sg = v * __builtin_amdgcn_rcpf(1.f + __expf(-v));
                        out2[row * 2048 + col] = f2bf(sg);
                    }
        }
    }
}

// ---------------- GEMM2: x_ssm[25600,80] = x_act[25600,2048] @ Wx[80,2048]^T ----------------
__global__ __launch_bounds__(256, 2)
void gemm2_kernel(const unsigned short* __restrict__ A,
                  const unsigned short* __restrict__ B,
                  float* __restrict__ out) {
    __shared__ __align__(16) unsigned short As[64 * 32];
    __shared__ __align__(16) unsigned short Bs[80 * 32];
    const int tid  = threadIdx.x;
    const int bm   = blockIdx.x;
    const int wid  = tid >> 6;
    const int lane = tid & 63;
    const int lrow = lane & 15;
    const int kq   = lane >> 4;

    f32x4 acc[5];
    #pragma unroll
    for (int i = 0; i < 5; i++) acc[i] = (f32x4){0.f, 0.f, 0.f, 0.f};

    const int r1 = tid >> 2;
    const int c8 = (tid & 3) << 3;
    const unsigned short* gA1 = A + ((size_t)bm * 64 + r1) * NDI + c8;
    const unsigned short* gB1 = B + (size_t)r1 * NDI + c8;
    const unsigned short* gB2 = B + (size_t)(64 + r1) * NDI + c8;
    char* lA1 = (char*)As + wid * 1024;
    char* lB1 = (char*)Bs + wid * 1024;
    char* lB2 = (char*)Bs + 4096;

    for (int kt = 0; kt < NDI; kt += 32) {
        __syncthreads();
        gl_lds16(gA1, lA1);
        gl_lds16(gB1, lB1);
        if (tid < 64) gl_lds16(gB2, lB2);
        gA1 += 32; gB1 += 32; gB2 += 32;
        __syncthreads();
        bf16x8 af = *(const bf16x8*)&As[(wid * 16 + lrow) * 32 + kq * 8];
        #pragma unroll
        for (int ni = 0; ni < 5; ni++) {
            bf16x8 bfr = *(const bf16x8*)&Bs[(ni * 16 + lrow) * 32 + kq * 8];
            acc[ni] = __builtin_amdgcn_mfma_f32_16x16x32_bf16(af, bfr, acc[ni], 0, 0, 0);
        }
    }
    #pragma unroll
    for (int ni = 0; ni < 5; ni++)
        #pragma unroll
        for (int r = 0; r < 4; r++) {
            size_t row = (size_t)bm * 64 + wid * 16 + kq * 4 + r;
            int col = ni * 16 + lrow;
            out[row * 80 + col] = acc[ni][r];
        }
}

// ================= SSD chunked selective scan =================
// Per block: (b, 256-d slice). 4 chunks of T=32 steps, h0 carried in LDS.
// y[t,d] = Einv[t,d]*( C@h0 + Gmask@P )[t,d],  P[s,d]=xa*exp(L'[s,d]),
// h0' = Einv[31,d]*(h0 + B^T@P).  G[t,s]=sum_n C[t,n]B[s,n] shared over d.
// Output g = y*zs written in-place over x_act (bf16); zs = silu(z) precomputed.
__global__ __launch_bounds__(256, 2)
void ssd_kernel(const float* __restrict__ xssm,          // [25600,80]: [dr | B(32) | C(32) | pad]
                unsigned short* xact_g,                   // in: x_act, out: g (bf16, in-place)
                const unsigned short* __restrict__ zs,    // silu(z) bf16 [25600,2048]
                const float* __restrict__ dtW,
                const float* __restrict__ dtb,
                const float* __restrict__ eb,             // [25600] f32
                const float* __restrict__ es_p) {
    __shared__ float sDR[32], sDE[32];
    __shared__ __align__(16) unsigned short sC[32][32];    // [t][n]
    __shared__ __align__(16) unsigned short sB[32][32];    // [s][n]
    __shared__ __align__(16) unsigned short sBt[32][32];   // [n][s]
    __shared__ __align__(16) unsigned short sG[32][32];    // [t][s] swz
    __shared__ __align__(16) unsigned short sP[256][32];   // [dloc][s] swz (wave-local)
    __shared__ __align__(16) float          sE[256][32];   // [dloc][t] swz, Einv=exp(-L')
    __shared__ __align__(16) unsigned short sH[256][32];   // [dloc][n] h0 bf16

    const int tid  = threadIdx.x;
    const int b    = blockIdx.y;
    const int d0   = blockIdx.x * 256;
    const int lane = tid & 63;
    const int wid  = tid >> 6;
    const int lrow = lane & 15;
    const int kq   = lane >> 4;
    const int wd0  = wid * 64;

    const float w  = dtW[d0 + tid];
    const float bb = dtb[d0 + tid];
    const float es = es_p[0];

    // h0 = 0
    for (int i = tid; i < 256 * 32; i += 256) ((unsigned short*)sH)[i] = 0;

    #pragma unroll 1
    for (int c = 0; c < 4; ++c) {
        __syncthreads();                         // protect staging vs prev readers
        // ---- stage xssm chunk slice + emotion bias ----
        {
            const float* src = xssm + ((size_t)b * 128 + c * 32) * 80;
            for (int i = tid; i < 2560; i += 256) {
                int t = i / 80, col = i - t * 80;
                float v = src[i];
                if (col == 0) sDR[t] = v;
                else if (col < 33) {
                    unsigned short bv = f2bf(v);
                    sB[t][col - 1] = bv;
                    sBt[col - 1][t] = bv;
                } else if (col < 65) sC[t][col - 33] = f2bf(v);
            }
            if (tid < 32) sDE[tid] = es * eb[b * 128 + c * 32 + tid];
        }
        __syncthreads();

        // ---- G = C B^T with causal mask (wave wid -> fragment wid) ----
        {
            int mi = wid >> 1, ni = wid & 1;
            bf16x8 af = *(const bf16x8*)&sC[mi * 16 + lrow][kq * 8];
            bf16x8 bf = *(const bf16x8*)&sB[ni * 16 + lrow][kq * 8];
            f32x4 z4 = (f32x4){0.f, 0.f, 0.f, 0.f};
            f32x4 g = __builtin_amdgcn_mfma_f32_16x16x32_bf16(af, bf, z4, 0, 0, 0);
            #pragma unroll
            for (int r = 0; r < 4; ++r) {
                int t = mi * 16 + kq * 4 + r, s = ni * 16 + lrow;
                float val = (s <= t) ? g[r] : 0.f;
                *(unsigned short*)((char*)sG + t * 64 +
                    ((((s >> 3) ^ (t & 3)) << 4) | ((s & 7) << 1))) = f2bf(val);
            }
        }

        // ---- P/E gen: serial 32-step prefix per thread (dloc = tid) ----
        {
            const unsigned short* pxa =
                xact_g + ((size_t)b * 128 + c * 32) * 2048 + d0 + tid;
            float L = 0.f;
            for (int t8 = 0; t8 < 4; ++t8) {
                bf16x8 pv;
                #pragma unroll
                for (int j = 0; j < 8; ++j) {
                    int t = t8 * 8 + j;
                    float raw = fmaf(sDR[t], w, bb);
                    float sp  = (raw > 20.f) ? raw : __logf(1.f + __expf(raw));
                    float delta = fmaxf(sp + sDE[t], 1e-4f);
                    L += delta;
                    float xa = bf2f(pxa[(size_t)t * 2048]);
                    pv[j] = (short)f2bf(xa * __expf(L));
                    *(float*)((char*)sE + tid * 128 +
                        ((((t >> 2) ^ (tid & 7)) << 4) | ((t & 3) << 2))) = __expf(-L);
                }
                *(bf16x8*)((char*)sP + tid * 64 + (((t8 ^ (tid & 3)) << 4))) = pv;
            }
        }
        __syncthreads();

        // ---- MFMA phase: acc = C@h0 + Gmask@P ; racc = B^T@P ----
        f32x4 acc[2][4], racc[2][4];
        bf16x8 cfrag[2], gfrag[2], btfrag[2], hfrag[4], pfrag[4];
        #pragma unroll
        for (int mi = 0; mi < 2; ++mi) {
            int tr = mi * 16 + lrow;
            cfrag[mi]  = *(const bf16x8*)&sC[tr][kq * 8];
            gfrag[mi]  = *(const bf16x8*)((const char*)sG + tr * 64 +
                                          (((kq ^ (tr & 3)) << 4)));
            btfrag[mi] = *(const bf16x8*)&sBt[tr][kq * 8];
        }
        #pragma unroll
        for (int ni = 0; ni < 4; ++ni) {
            int dc = wd0 + ni * 16 + lrow;
            hfrag[ni] = *(const bf16x8*)&sH[dc][kq * 8];
            pfrag[ni] = *(const bf16x8*)((const char*)sP + dc * 64 +
                                         (((kq ^ (dc & 3)) << 4)));
        }
        #pragma unroll
        for (int mi = 0; mi < 2; ++mi)
            #pragma unroll
            for (int ni = 0; ni < 4; ++ni) {
                f32x4 z4 = (f32x4){0.f, 0.f, 0.f, 0.f};
                acc[mi][ni] = __builtin_amdgcn_mfma_f32_16x16x32_bf16(
                    cfrag[mi], hfrag[ni], z4, 0, 0, 0);
                acc[mi][ni] = __builtin_amdgcn_mfma_f32_16x16x32_bf16(
                    gfrag[mi], pfrag[ni], acc[mi][ni], 0, 0, 0);
                racc[mi][ni] = __builtin_amdgcn_mfma_f32_16x16x32_bf16(
                    btfrag[mi], pfrag[ni], z4, 0, 0, 0);
            }

        // ---- epilogue: g = Einv*acc * zs, in-place over x_act ----
        #pragma unroll
        for (int mi = 0; mi < 2; ++mi)
            #pragma unroll
            for (int ni = 0; ni < 4; ++ni) {
                int dc = wd0 + ni * 16 + lrow;
                f32x4 ev = *(const f32x4*)((const char*)sE + dc * 128 +
                                           ((((mi * 4 + kq) ^ (dc & 7)) << 4)));
                size_t rowg = (size_t)b * 128 + c * 32 + mi * 16 + kq * 4;
                #pragma unroll
                for (int r = 0; r < 4; ++r) {
                    size_t gi = (rowg + r) * 2048 + d0 + dc;
                    float y  = acc[mi][ni][r] * ev[r];
                    xact_g[gi] = f2bf(y * bf2f(zs[gi]));
                }
            }

        // ---- h0 update (wave-local d range): h0' = Einv[31]*(h0 + R) ----
        #pragma unroll
        for (int ni = 0; ni < 4; ++ni) {
            int dc = wd0 + ni * 16 + lrow;
            float e31 = *(const float*)((const char*)sE + dc * 128 +
                                        (((7 ^ (dc & 7)) << 4) | 12));
            #pragma unroll
            for (int mi = 0; mi < 2; ++mi)
                #pragma unroll
                for (int r = 0; r < 4; ++r) {
                    int n = mi * 16 + kq * 4 + r;
                    float h = bf2f(sH[dc][n]) + racc[mi][ni][r];
                    sH[dc][n] = f2bf(e31 * h);
                }
        }
    }
}

// ---------------- launch ----------------
extern "C" void kernel_launch(void* const* d_in, const int* in_sizes, int n_in,
                              void* d_out, int out_size, void* d_ws, size_t ws_size,
                              hipStream_t stream) {
    const float* x   = (const float*)d_in[0];
    const float* eb  = (const float*)d_in[1];
    const float* nw  = (const float*)d_in[2];
    const float* nb  = (const float*)d_in[3];
    const float* Wi  = (const float*)d_in[4];
    const float* cw  = (const float*)d_in[5];
    const float* cb  = (const float*)d_in[6];
    const float* Wx  = (const float*)d_in[7];
    const float* dtW = (const float*)d_in[8];
    const float* dtb = (const float*)d_in[9];
    const float* Wo  = (const float*)d_in[10];
    const float* es  = (const float*)d_in[11];
    float* out = (float*)d_out;                     // FLOAT32 output

    // workspace layout (bytes, 256-aligned)
    char* ws = (char*)d_ws;
    unsigned short* wi_b   = (unsigned short*)(ws + 0);            //   8,388,608
    unsigned short* wo_b   = (unsigned short*)(ws + 8388608);      //   4,194,304
    unsigned short* wx_b   = (unsigned short*)(ws + 12582912);     //     327,680
    unsigned short* zs_b   = (unsigned short*)(ws + 12910592);     // 104,857,600 silu(z)
    unsigned short* xn_b   = (unsigned short*)(ws + 117768192);    //  52,428,800
    unsigned short* xact_b = (unsigned short*)(ws + 170196992);    // 104,857,600
    float*          xssm   = (float*)(ws + 275054592);             //   8,192,000 -> 283,246,592
    if (ws_size < (size_t)283246592) return;

    // 1. weights -> bf16
    cvt_kernel<<<(2 * NDI * ND + 255) / 256, 256, 0, stream>>>(Wi, wi_b, 2 * NDI * ND);
    cvt_kernel<<<(ND * NDI + 255) / 256, 256, 0, stream>>>(Wo, wo_b, ND * NDI);
    padwx_kernel<<<(80 * NDI) / 256, 256, 0, stream>>>(Wx, wx_b);

    // 2. LayerNorm -> xn (bf16)
    ln_kernel<<<NROWS, 256, 0, stream>>>(x, nw, nb, xn_b);

    // 3. GEMM1 fused: x_act = silu(conv(xn @ Wi^T[:,0:2048])), zs = silu(z-half)
    gemm256<ND, 2><<<dim3(NROWS / 256, (2 * NDI) / 256), 512, 0, stream>>>(
        xn_b, wi_b, 2 * NDI, xact_b, nullptr, cw, cb, zs_b);

    // 4. GEMM2: x_ssm = x_act @ Wx^T  [25600,80] f32
    gemm2_kernel<<<NROWS / 64, 256, 0, stream>>>(xact_b, wx_b, xssm);

    // 5. SSD chunked scan + gating (g overwrites x_act)
    ssd_kernel<<<dim3(NDI / 256, NBN), 256, 0, stream>>>(xssm, xact_b, zs_b, dtW, dtb, eb, es);

    // 6. GEMM3: out = g @ Wo^T + residual  (f32 nontemporal store)
    gemm256<NDI, 1><<<dim3(NROWS / 256, ND / 256), 512, 0, stream>>>(
        xact_b, wo_b, ND, out, x, nullptr, nullptr, nullptr);
}